// Round 6
// baseline (242.097 us; speedup 1.0000x reference)
//
#include <hip/hip_runtime.h>

// EFDM loss — reduced form:
//   pos_sum[b]  = sum over (a,p,c,j) of (sortT[a,p,b,c][j] - sortS[a,p,b,c][j])^2
//   neg_sum[b]  = sum over (a,p,k,c,j) of (sortT[a,p,b,c][j] - sortS[a,p,nb(b,k),c][j])^2
//   out = sum_b pos_sum[b]/neg_sum[b]          (the 1/(C*N) mean factors cancel)
//
// Register bitonic sort, 16 elems/thread, 256 thr/row.
//  - sign-negation trick -> all compares static min/max (+cndmask for per-lane side)
//  - ALL lane-xor exchanges via DPP (zero ds_swizzle):
//      xor1 = quad_perm 0xB1, xor2 = quad_perm 0x4E,
//      xor4 = quad_perm 0x1B (xor3) o row_half_mirror 0x141 (xor7),
//      xor8 = row_ror:8 (0x128)
//    xor16/32 via paired v_permlane16/32_swap (VALU)
//  - thread-xor 64/128 via LDS float4 (stride-20 rows, conflict-free) — only DS use

constexpr int N    = 4096;
constexpr int NTH  = 256;
constexpr int CDIM = 128;
constexpr int BDIM = 4;
constexpr int KNEG = 2;
constexpr int ROWS = 4096;
constexpr int HALF = 2048;
constexpr int LSTR = 20;   // floats per thread-row in LDS: 80B, 16B-aligned;
                           // 16B-block stride 5 (mod 8) -> conflict-free b128

__device__ inline unsigned fasu(float x) { return __float_as_uint(x); }
__device__ inline float    usaf(unsigned x) { return __uint_as_float(x); }

__device__ inline void cswap_asc(float& a, float& b) {
  const float lo = fminf(a, b), hi = fmaxf(a, b);
  a = lo; b = hi;
}

// pre-stages k=2,4,8: direction static from local index m
template<int K, int J>
__device__ inline void local_pass(float v[16]) {
  #pragma unroll
  for (int m = 0; m < 16; ++m)
    if ((m & J) == 0) {
      if ((m & K) == 0) cswap_asc(v[m], v[m ^ J]);
      else              cswap_asc(v[m ^ J], v[m]);
    }
}

// ascending in-register tail: j = J, J/2, .., 1
template<int J>
__device__ inline void reg_passes_asc(float v[16]) {
  if constexpr (J >= 1) {
    #pragma unroll
    for (int m = 0; m < 16; ++m)
      if ((m & J) == 0) cswap_asc(v[m], v[m ^ J]);
    reg_passes_asc<(J >> 1)>(v);
  }
}

// DPP lane exchange. ctrls: 0xB1=quad[1,0,3,2](xor1)  0x4E=quad[2,3,0,1](xor2)
// 0x1B=quad[3,2,1,0](xor3)  0x141=row_half_mirror(xor7)  0x128=row_ror:8(xor8)
template<int CTRL>
__device__ inline float dpp_x(float x) {
  const int s = (int)fasu(x);
  return usaf((unsigned)__builtin_amdgcn_update_dpp(s, s, CTRL, 0xF, 0xF, false));
}

// lane-xor TM in {1,2,4,8}, all DPP: per-lane keep-min = ((t&TM)==0).
// Batched in groups of 8 for exchange/minmax overlap.
template<int TM>
__device__ inline void pass_small(float v[16], int t) {
  const bool km = ((t & TM) == 0);
  #pragma unroll
  for (int g = 0; g < 16; g += 8) {
    float o[8];
    #pragma unroll
    for (int m = 0; m < 8; ++m) {
      if constexpr (TM == 1)      o[m] = dpp_x<0xB1>(v[g + m]);
      else if constexpr (TM == 2) o[m] = dpp_x<0x4E>(v[g + m]);
      else if constexpr (TM == 4) o[m] = dpp_x<0x141>(dpp_x<0x1B>(v[g + m]));
      else                        o[m] = dpp_x<0x128>(v[g + m]);
    }
    #pragma unroll
    for (int m = 0; m < 8; ++m)
      v[g + m] = km ? fminf(v[g + m], o[m]) : fmaxf(v[g + m], o[m]);
  }
}

// gfx950 permlane swaps: both operands read AND written.
__device__ inline void swap32(float& a, float& b) {
  asm("v_permlane32_swap_b32 %0, %1" : "+v"(a), "+v"(b));
}
__device__ inline void swap16(float& a, float& b) {
  asm("v_permlane16_swap_b32 %0, %1" : "+v"(a), "+v"(b));
}

// lane-xor 16/32 butterfly on element PAIRs, 4 pairs at a time:
// 2 swaps + min + max -> both results, min landing in the (t&TM)==0 lanes.
template<bool IS32>
__device__ inline void pass_perm(float v[16]) {
  #pragma unroll
  for (int g = 0; g < 16; g += 8) {
    float a[4], b[4];
    #pragma unroll
    for (int p = 0; p < 4; ++p) {
      a[p] = v[g + 2*p]; b[p] = v[g + 2*p + 1];
      if constexpr (IS32) swap32(a[p], b[p]); else swap16(a[p], b[p]);
    }
    #pragma unroll
    for (int p = 0; p < 4; ++p) {
      float mn = fminf(a[p], b[p]);
      float mx = fmaxf(a[p], b[p]);
      if constexpr (IS32) swap32(mn, mx); else swap16(mn, mx);
      v[g + 2*p] = mn; v[g + 2*p + 1] = mx;
    }
  }
}

// thread-xor 64/128 via LDS (float4 path); keep decision wave-uniform
template<int TM>
__device__ inline void pass_lds(float v[16], float* buf, int t) {
  __syncthreads();   // protect prior reads of buf
  float4* wp = (float4*)(buf + t * LSTR);
  #pragma unroll
  for (int q = 0; q < 4; ++q)
    wp[q] = make_float4(v[q*4+0], v[q*4+1], v[q*4+2], v[q*4+3]);
  __syncthreads();
  const float4* rp = (const float4*)(buf + (t ^ TM) * LSTR);
  float4 x[4];
  #pragma unroll
  for (int q = 0; q < 4; ++q) x[q] = rp[q];
  if (t & TM) {
    #pragma unroll
    for (int q = 0; q < 4; ++q) {
      v[q*4+0] = fmaxf(v[q*4+0], x[q].x); v[q*4+1] = fmaxf(v[q*4+1], x[q].y);
      v[q*4+2] = fmaxf(v[q*4+2], x[q].z); v[q*4+3] = fmaxf(v[q*4+3], x[q].w);
    }
  } else {
    #pragma unroll
    for (int q = 0; q < 4; ++q) {
      v[q*4+0] = fminf(v[q*4+0], x[q].x); v[q*4+1] = fminf(v[q*4+1], x[q].y);
      v[q*4+2] = fminf(v[q*4+2], x[q].z); v[q*4+3] = fminf(v[q*4+3], x[q].w);
    }
  }
}

template<int K, int J>
__device__ inline void cross_passes(float v[16], float* buf, int t) {
  if constexpr (J >= 16) {
    constexpr int TM = J >> 4;
    if constexpr (TM >= 64)      pass_lds<TM>(v, buf, t);
    else if constexpr (TM == 32) pass_perm<true>(v);
    else if constexpr (TM == 16) pass_perm<false>(v);
    else                         pass_small<TM>(v, t);
    cross_passes<K, (J >> 1)>(v, buf, t);
  }
}

__device__ inline void apply_flip(float v[16], unsigned f) {
  #pragma unroll
  for (int m = 0; m < 16; ++m) v[m] = usaf(fasu(v[m]) ^ f);
}

// one bitonic stage of width K (>=16), in sign-flipped space
template<int K>
__device__ inline void stage_n(float v[16], float* buf, int t, unsigned& cur) {
  const unsigned f = (t & (K >> 4)) ? 0x80000000u : 0u;
  apply_flip(v, f ^ cur);
  cur = f;
  cross_passes<K, (K >> 1)>(v, buf, t);
  reg_passes_asc<8>(v);
}

// full ascending sort of 4096 floats: v[16] per thread, i = t*16+m
__device__ inline void sort4096(float v[16], float* buf, int t) {
  local_pass<2, 1>(v);
  local_pass<4, 2>(v); local_pass<4, 1>(v);
  local_pass<8, 4>(v); local_pass<8, 2>(v); local_pass<8, 1>(v);
  unsigned cur = 0;
  stage_n<16>(v, buf, t, cur);
  stage_n<32>(v, buf, t, cur);
  stage_n<64>(v, buf, t, cur);
  stage_n<128>(v, buf, t, cur);
  stage_n<256>(v, buf, t, cur);
  stage_n<512>(v, buf, t, cur);
  stage_n<1024>(v, buf, t, cur);
  stage_n<2048>(v, buf, t, cur);
  stage_n<4096>(v, buf, t, cur);
  apply_flip(v, cur);   // cur == 0 for all t<256, but keep it general
}

__device__ inline void load16(const float* __restrict__ src, float v[16], int t) {
  const float4* s4 = (const float4*)src;
  #pragma unroll
  for (int q = 0; q < 4; ++q) {
    const float4 x = s4[t * 4 + q];
    v[q * 4 + 0] = x.x; v[q * 4 + 1] = x.y;
    v[q * 4 + 2] = x.z; v[q * 4 + 3] = x.w;
  }
}

__global__ __launch_bounds__(NTH)
__attribute__((amdgpu_waves_per_eu(8)))
void sort_rows(const float* __restrict__ a0, const float* __restrict__ a1,
               float* __restrict__ out) {
  __shared__ float buf[NTH * LSTR];
  const int t = threadIdx.x;
  const int r = blockIdx.x;
  const float* src = (r < HALF) ? a0 + (size_t)r * N
                                : a1 + (size_t)(r - HALF) * N;
  float v[16];
  load16(src, v, t);
  sort4096(v, buf, t);
  float4* d4 = (float4*)(out + (size_t)r * N);
  #pragma unroll
  for (int q = 0; q < 4; ++q)
    d4[t * 4 + q] = make_float4(v[q*4+0], v[q*4+1], v[q*4+2], v[q*4+3]);
}

__global__ __launch_bounds__(NTH)
__attribute__((amdgpu_waves_per_eu(8)))
void loss_rows(const float* __restrict__ t0, const float* __restrict__ t1,
               const float* __restrict__ Vs, const int* __restrict__ neg_idx,
               double* __restrict__ acc) {
  __shared__ float buf[NTH * LSTR];
  __shared__ float red[2][4];
  const int t = threadIdx.x;
  const int r = blockIdx.x;
  const float* src = (r < HALF) ? t0 + (size_t)r * N
                                : t1 + (size_t)(r - HALF) * N;
  float v[16];
  load16(src, v, t);
  sort4096(v, buf, t);

  // r = ((ap)*B + b)*C + c
  const int c  = r & (CDIM - 1);
  const int b  = (r / CDIM) & (BDIM - 1);
  const int ap = r / (CDIM * BDIM);

  float posp = 0.f, negp = 0.f;
  {
    const float4* vp4 = (const float4*)(Vs + (size_t)r * N);
    #pragma unroll
    for (int q = 0; q < 4; ++q) {
      const float4 x = vp4[t * 4 + q];
      float d0 = v[q*4+0] - x.x, d1 = v[q*4+1] - x.y;
      float d2 = v[q*4+2] - x.z, d3 = v[q*4+3] - x.w;
      posp += d0*d0 + d1*d1 + d2*d2 + d3*d3;
    }
  }
  #pragma unroll
  for (int k = 0; k < KNEG; ++k) {
    const int nb = neg_idx[b * KNEG + k];
    const float4* vn4 = (const float4*)(Vs + ((size_t)(ap * BDIM + nb) * CDIM + c) * N);
    #pragma unroll
    for (int q = 0; q < 4; ++q) {
      const float4 x = vn4[t * 4 + q];
      float d0 = v[q*4+0] - x.x, d1 = v[q*4+1] - x.y;
      float d2 = v[q*4+2] - x.z, d3 = v[q*4+3] - x.w;
      negp += d0*d0 + d1*d1 + d2*d2 + d3*d3;
    }
  }

  #pragma unroll
  for (int off = 32; off > 0; off >>= 1) {
    posp += __shfl_down(posp, off, 64);
    negp += __shfl_down(negp, off, 64);
  }
  const int wid = t >> 6, lane = t & 63;
  if (lane == 0) { red[0][wid] = posp; red[1][wid] = negp; }
  __syncthreads();
  if (t == 0) {
    const float pt = red[0][0] + red[0][1] + red[0][2] + red[0][3];
    const float nt = red[1][0] + red[1][1] + red[1][2] + red[1][3];
    atomicAdd(&acc[b], (double)pt);
    atomicAdd(&acc[BDIM + b], (double)nt);
  }
}

__global__ void finalize(const double* __restrict__ acc, float* __restrict__ out) {
  if (threadIdx.x == 0 && blockIdx.x == 0) {
    double s = 0.0;
    for (int b = 0; b < BDIM; ++b) s += acc[b] / acc[BDIM + b];
    out[0] = (float)s;
  }
}

extern "C" void kernel_launch(void* const* d_in, const int* in_sizes, int n_in,
                              void* d_out, int out_size, void* d_ws, size_t ws_size,
                              hipStream_t stream) {
  const float* style_E = (const float*)d_in[0];
  const float* style_S = (const float*)d_in[1];
  const float* trans_E = (const float*)d_in[2];
  const float* trans_S = (const float*)d_in[3];
  const int*   neg_idx = (const int*)d_in[4];

  double* acc = (double*)d_ws;
  float*  Vs  = (float*)((char*)d_ws + 256);

  hipMemsetAsync(d_ws, 0, 256, stream);
  sort_rows<<<ROWS, NTH, 0, stream>>>(style_E, style_S, Vs);
  loss_rows<<<ROWS, NTH, 0, stream>>>(trans_E, trans_S, Vs, neg_idx, acc);
  finalize<<<1, 64, 0, stream>>>(acc, (float*)d_out);
}

// Round 8
// 171.625 us; speedup vs baseline: 1.4106x; 1.4106x over previous
//
#include <hip/hip_runtime.h>

// EFDM loss — reduced form:
//   pos_sum[b]  = sum over (a,p,c,j) of (sortT[a,p,b,c][j] - sortS[a,p,b,c][j])^2
//   neg_sum[b]  = sum over (a,p,k,c,j) of (sortT[a,p,b,c][j] - sortS[a,p,nb(b,k),c][j])^2
//   out = sum_b pos_sum[b]/neg_sum[b]          (the 1/(C*N) mean factors cancel)
//
// PACKED fp16 register bitonic sort: 16 elems/thread as 8 x (2xfp16) words,
// 256 thr/row. Packing (m, m+8) per word. Every compare-exchange, lane
// exchange, LDS word and cndmask now processes TWO elements per instruction:
//  - pre-stages k=2..8 in f32 (cheap), then v_cvt_pkrtz pack (monotone RTZ)
//  - tail j=8: 3-op within-word sort (pk_min/pk_max with op_sel + merge)
//  - tail j=4,2,1: pk_min/pk_max on register pairs (0.5 op/elem)
//  - lane-xor 1/2/4/8 via DPP on packed words; 16/32 via permlane swaps
//  - thread-xor 64/128 via LDS uint4 (stride-20 words, conflict-free)
//  - diff phase: v_pk_add_f16(neg) + v_dot2_f32_f16 accumulate in f32
// fp16 rounding error on the final scalar ~1e-4 vs threshold 4e-2.

typedef unsigned int u32;
typedef __fp16 f16x2 __attribute__((ext_vector_type(2)));

constexpr int N     = 4096;
constexpr int NTH   = 256;
constexpr int CDIM  = 128;
constexpr int BDIM  = 4;
constexpr int KNEG  = 2;
constexpr int ROWS  = 4096;
constexpr int HALF  = 2048;
constexpr int LSTRW = 20;      // u32 per thread-row in LDS (80B, 16B-aligned, conflict-free)
constexpr int ROWW  = N / 2;   // 2048 packed words per row

// ---------- packed fp16 primitives ----------
__device__ inline u32 pk_min(u32 a, u32 b) {
  u32 d; asm("v_pk_min_f16 %0, %1, %2" : "=v"(d) : "v"(a), "v"(b)); return d;
}
__device__ inline u32 pk_max(u32 a, u32 b) {
  u32 d; asm("v_pk_max_f16 %0, %1, %2" : "=v"(d) : "v"(a), "v"(b)); return d;
}
// d.lo = min(a.lo, a.hi)   (hi half = same min, unused)
__device__ inline u32 pk_min_swap(u32 a) {
  u32 d; asm("v_pk_min_f16 %0, %1, %1 op_sel:[0,1] op_sel_hi:[1,0]" : "=v"(d) : "v"(a)); return d;
}
// d.hi = max(a.lo, a.hi)
__device__ inline u32 pk_max_swap(u32 a) {
  u32 d; asm("v_pk_max_f16 %0, %1, %1 op_sel:[0,1] op_sel_hi:[1,0]" : "=v"(d) : "v"(a)); return d;
}
__device__ inline u32 pk_sub(u32 a, u32 b) {   // a - b per half
  u32 d; asm("v_pk_add_f16 %0, %1, %2 neg_lo:[0,1] neg_hi:[0,1]" : "=v"(d) : "v"(a), "v"(b)); return d;
}
__device__ inline float dot2acc(u32 d, float acc) {  // acc += d.lo^2 + d.hi^2 (f32 internal)
  asm("v_dot2_f32_f16 %0, %1, %2, %0" : "+v"(acc) : "v"(d), "v"(d)); return acc;
}

__device__ inline void pk_cswap(u32& a, u32& b) {
  const u32 mn = pk_min(a, b), mx = pk_max(a, b);
  a = mn; b = mx;
}
// sort the two halves within one word: lo' = min, hi' = max
__device__ inline u32 pk_sort_pair(u32 a) {
  const u32 mn = pk_min_swap(a);
  const u32 mx = pk_max_swap(a);
  return (mx & 0xFFFF0000u) | (mn & 0x0000FFFFu);
}

// ---------- f32 pre-stage (k <= 8), verified structure ----------
__device__ inline void cswap_asc(float& a, float& b) {
  const float lo = fminf(a, b), hi = fmaxf(a, b);
  a = lo; b = hi;
}
template<int K, int J>
__device__ inline void local_pass(float v[16]) {
  #pragma unroll
  for (int m = 0; m < 16; ++m)
    if ((m & J) == 0) {
      if ((m & K) == 0) cswap_asc(v[m], v[m ^ J]);
      else              cswap_asc(v[m ^ J], v[m]);
    }
}

// ---------- cross-lane exchanges on packed words ----------
// DPP ctrls: 0xB1=quad xor1, 0x4E=quad xor2, 0x1B=quad xor3,
//            0x141=row_half_mirror (xor7), 0x128=row_ror:8 (xor8)
template<int CTRL>
__device__ inline u32 dpp_u(u32 x) {
  return (u32)__builtin_amdgcn_update_dpp((int)x, (int)x, CTRL, 0xF, 0xF, false);
}

template<int TM>   // TM in {1,2,4,8}: per-lane keep-min = ((t&TM)==0)
__device__ inline void pass_small_pk(u32 h[8], int t) {
  const bool km = ((t & TM) == 0);
  u32 o[8];
  #pragma unroll
  for (int p = 0; p < 8; ++p) {
    if constexpr (TM == 1)      o[p] = dpp_u<0xB1>(h[p]);
    else if constexpr (TM == 2) o[p] = dpp_u<0x4E>(h[p]);
    else if constexpr (TM == 4) o[p] = dpp_u<0x141>(dpp_u<0x1B>(h[p]));
    else                        o[p] = dpp_u<0x128>(h[p]);
  }
  #pragma unroll
  for (int p = 0; p < 8; ++p) {
    const u32 mn = pk_min(h[p], o[p]), mx = pk_max(h[p], o[p]);
    h[p] = km ? mn : mx;
  }
}

// gfx950 permlane swaps (both operands read AND written)
__device__ inline void swap32u(u32& a, u32& b) {
  asm("v_permlane32_swap_b32 %0, %1" : "+v"(a), "+v"(b));
}
__device__ inline void swap16u(u32& a, u32& b) {
  asm("v_permlane16_swap_b32 %0, %1" : "+v"(a), "+v"(b));
}
// lane-xor 16/32 butterfly on word PAIRs: 2 swaps + pk_min + pk_max -> both
// results, min landing in the (t&TM)==0 lanes. 1 op/elem.
template<bool IS32>
__device__ inline void pass_perm_pk(u32 h[8]) {
  #pragma unroll
  for (int q = 0; q < 4; ++q) {
    u32 a = h[2*q], b = h[2*q + 1];
    if constexpr (IS32) swap32u(a, b); else swap16u(a, b);
    u32 mn = pk_min(a, b);
    u32 mx = pk_max(a, b);
    if constexpr (IS32) swap32u(mn, mx); else swap16u(mn, mx);
    h[2*q] = mn; h[2*q + 1] = mx;
  }
}

// thread-xor 64/128 via LDS; keep decision wave-uniform
template<int TM>
__device__ inline void pass_lds_pk(u32 h[8], u32* buf, int t) {
  __syncthreads();   // protect prior reads of buf
  uint4* wp = (uint4*)(buf + t * LSTRW);
  wp[0] = make_uint4(h[0], h[1], h[2], h[3]);
  wp[1] = make_uint4(h[4], h[5], h[6], h[7]);
  __syncthreads();
  const uint4* rp = (const uint4*)(buf + (t ^ TM) * LSTRW);
  const uint4 x0 = rp[0], x1 = rp[1];
  if (t & TM) {
    h[0] = pk_max(h[0], x0.x); h[1] = pk_max(h[1], x0.y);
    h[2] = pk_max(h[2], x0.z); h[3] = pk_max(h[3], x0.w);
    h[4] = pk_max(h[4], x1.x); h[5] = pk_max(h[5], x1.y);
    h[6] = pk_max(h[6], x1.z); h[7] = pk_max(h[7], x1.w);
  } else {
    h[0] = pk_min(h[0], x0.x); h[1] = pk_min(h[1], x0.y);
    h[2] = pk_min(h[2], x0.z); h[3] = pk_min(h[3], x0.w);
    h[4] = pk_min(h[4], x1.x); h[5] = pk_min(h[5], x1.y);
    h[6] = pk_min(h[6], x1.z); h[7] = pk_min(h[7], x1.w);
  }
}

template<int K, int J>
__device__ inline void cross_pk(u32 h[8], u32* buf, int t) {
  if constexpr (J >= 16) {
    constexpr int TM = J >> 4;
    if constexpr (TM >= 64)      pass_lds_pk<TM>(h, buf, t);
    else if constexpr (TM == 32) pass_perm_pk<true>(h);
    else if constexpr (TM == 16) pass_perm_pk<false>(h);
    else                         pass_small_pk<TM>(h, t);
    cross_pk<K, (J >> 1)>(h, buf, t);
  }
}

// in-register ascending tail: j = 8 (within-word), then 4, 2, 1 (cross-word)
__device__ inline void tail_pk(u32 h[8]) {
  #pragma unroll
  for (int p = 0; p < 8; ++p) h[p] = pk_sort_pair(h[p]);
  pk_cswap(h[0], h[4]); pk_cswap(h[1], h[5]); pk_cswap(h[2], h[6]); pk_cswap(h[3], h[7]);
  pk_cswap(h[0], h[2]); pk_cswap(h[1], h[3]); pk_cswap(h[4], h[6]); pk_cswap(h[5], h[7]);
  pk_cswap(h[0], h[1]); pk_cswap(h[2], h[3]); pk_cswap(h[4], h[5]); pk_cswap(h[6], h[7]);
}

__device__ inline void flip_pk(u32 h[8], u32 f) {
  #pragma unroll
  for (int p = 0; p < 8; ++p) h[p] ^= f;
}

// one bitonic stage of width K (>=16), in sign-flipped space
template<int K>
__device__ inline void stage_pk(u32 h[8], u32* buf, int t, u32& cur) {
  const u32 f = (t & (K >> 4)) ? 0x80008000u : 0u;
  flip_pk(h, f ^ cur);
  cur = f;
  cross_pk<K, (K >> 1)>(h, buf, t);
  tail_pk(h);
}

// load 16 f32, pre-sort k<=8 in f32, pack to 8 fp16x2 words (m, m+8)
__device__ inline void load_prestage_pack(const float* __restrict__ src,
                                          u32 h[8], int t) {
  float v[16];
  const float4* s4 = (const float4*)src;
  #pragma unroll
  for (int q = 0; q < 4; ++q) {
    const float4 x = s4[t * 4 + q];
    v[q*4+0] = x.x; v[q*4+1] = x.y; v[q*4+2] = x.z; v[q*4+3] = x.w;
  }
  local_pass<2, 1>(v);
  local_pass<4, 2>(v); local_pass<4, 1>(v);
  local_pass<8, 4>(v); local_pass<8, 2>(v); local_pass<8, 1>(v);
  // after k=8: v[0..7] ascending, v[8..15] descending -> bitonic-16, pack
  #pragma unroll
  for (int p = 0; p < 8; ++p) {
    const f16x2 pk = __builtin_amdgcn_cvt_pkrtz(v[p], v[p + 8]);
    h[p] = __builtin_bit_cast(u32, pk);
  }
}

// full ascending sort: packed stages k=16..4096
__device__ inline void sort4096_pk(u32 h[8], u32* buf, int t) {
  u32 cur = 0;
  stage_pk<16>(h, buf, t, cur);
  stage_pk<32>(h, buf, t, cur);
  stage_pk<64>(h, buf, t, cur);
  stage_pk<128>(h, buf, t, cur);
  stage_pk<256>(h, buf, t, cur);
  stage_pk<512>(h, buf, t, cur);
  stage_pk<1024>(h, buf, t, cur);
  stage_pk<2048>(h, buf, t, cur);
  stage_pk<4096>(h, buf, t, cur);
  // cur == 0 here for all t<256 (K>>4 = 256 > tmax), no final unflip needed
}

__global__ __launch_bounds__(NTH)
void sort_rows(const float* __restrict__ a0, const float* __restrict__ a1,
               u32* __restrict__ out) {
  __shared__ u32 buf[NTH * LSTRW];
  const int t = threadIdx.x, r = blockIdx.x;
  const float* src = (r < HALF) ? a0 + (size_t)r * N
                                : a1 + (size_t)(r - HALF) * N;
  u32 h[8];
  load_prestage_pack(src, h, t);
  sort4096_pk(h, buf, t);
  uint4* d4 = (uint4*)(out + (size_t)r * ROWW);
  d4[t*2]     = make_uint4(h[0], h[1], h[2], h[3]);
  d4[t*2 + 1] = make_uint4(h[4], h[5], h[6], h[7]);
}

__global__ __launch_bounds__(NTH)
void loss_rows(const float* __restrict__ t0, const float* __restrict__ t1,
               const u32* __restrict__ Vs, const int* __restrict__ neg_idx,
               double* __restrict__ acc) {
  __shared__ u32 buf[NTH * LSTRW];
  __shared__ float red[2][4];
  const int t = threadIdx.x, r = blockIdx.x;
  const float* src = (r < HALF) ? t0 + (size_t)r * N
                                : t1 + (size_t)(r - HALF) * N;
  u32 h[8];
  load_prestage_pack(src, h, t);
  sort4096_pk(h, buf, t);

  // r = ((ap)*B + b)*C + c
  const int c  = r & (CDIM - 1);
  const int b  = (r / CDIM) & (BDIM - 1);
  const int ap = r / (CDIM * BDIM);

  float posp = 0.f, negp = 0.f;
  {
    const uint4* vp = (const uint4*)(Vs + (size_t)r * ROWW);
    const uint4 w0 = vp[t*2], w1 = vp[t*2 + 1];
    posp = dot2acc(pk_sub(h[0], w0.x), posp);
    posp = dot2acc(pk_sub(h[1], w0.y), posp);
    posp = dot2acc(pk_sub(h[2], w0.z), posp);
    posp = dot2acc(pk_sub(h[3], w0.w), posp);
    posp = dot2acc(pk_sub(h[4], w1.x), posp);
    posp = dot2acc(pk_sub(h[5], w1.y), posp);
    posp = dot2acc(pk_sub(h[6], w1.z), posp);
    posp = dot2acc(pk_sub(h[7], w1.w), posp);
  }
  #pragma unroll
  for (int k = 0; k < KNEG; ++k) {
    const int nb = neg_idx[b * KNEG + k];
    const uint4* vp = (const uint4*)(Vs + ((size_t)(ap * BDIM + nb) * CDIM + c) * ROWW);
    const uint4 w0 = vp[t*2], w1 = vp[t*2 + 1];
    negp = dot2acc(pk_sub(h[0], w0.x), negp);
    negp = dot2acc(pk_sub(h[1], w0.y), negp);
    negp = dot2acc(pk_sub(h[2], w0.z), negp);
    negp = dot2acc(pk_sub(h[3], w0.w), negp);
    negp = dot2acc(pk_sub(h[4], w1.x), negp);
    negp = dot2acc(pk_sub(h[5], w1.y), negp);
    negp = dot2acc(pk_sub(h[6], w1.z), negp);
    negp = dot2acc(pk_sub(h[7], w1.w), negp);
  }

  #pragma unroll
  for (int off = 32; off > 0; off >>= 1) {
    posp += __shfl_down(posp, off, 64);
    negp += __shfl_down(negp, off, 64);
  }
  const int wid = t >> 6, lane = t & 63;
  if (lane == 0) { red[0][wid] = posp; red[1][wid] = negp; }
  __syncthreads();
  if (t == 0) {
    const float pt = red[0][0] + red[0][1] + red[0][2] + red[0][3];
    const float nt = red[1][0] + red[1][1] + red[1][2] + red[1][3];
    atomicAdd(&acc[b], (double)pt);
    atomicAdd(&acc[BDIM + b], (double)nt);
  }
}

__global__ void finalize(const double* __restrict__ acc, float* __restrict__ out) {
  if (threadIdx.x == 0 && blockIdx.x == 0) {
    double s = 0.0;
    for (int b = 0; b < BDIM; ++b) s += acc[b] / acc[BDIM + b];
    out[0] = (float)s;
  }
}

extern "C" void kernel_launch(void* const* d_in, const int* in_sizes, int n_in,
                              void* d_out, int out_size, void* d_ws, size_t ws_size,
                              hipStream_t stream) {
  const float* style_E = (const float*)d_in[0];
  const float* style_S = (const float*)d_in[1];
  const float* trans_E = (const float*)d_in[2];
  const float* trans_S = (const float*)d_in[3];
  const int*   neg_idx = (const int*)d_in[4];

  // ws layout: [0,256): 2*B double accumulators; [256, 256+16.8MB): packed Vs
  double* acc = (double*)d_ws;
  u32*    Vs  = (u32*)((char*)d_ws + 256);

  (void)hipMemsetAsync(d_ws, 0, 256, stream);
  sort_rows<<<ROWS, NTH, 0, stream>>>(style_E, style_S, Vs);
  loss_rows<<<ROWS, NTH, 0, stream>>>(trans_E, trans_S, Vs, neg_idx, acc);
  finalize<<<1, 64, 0, stream>>>(acc, (float*)d_out);
}

// Round 9
// 126.648 us; speedup vs baseline: 1.9116x; 1.3551x over previous
//
#include <hip/hip_runtime.h>

// EFDM loss — reduced form:
//   pos_sum[b]  = sum over (a,p,c,j) of (sortT[a,p,b,c][j] - sortS[a,p,b,c][j])^2
//   neg_sum[b]  = sum over (a,p,k,c,j) of (sortT[a,p,b,c][j] - sortS[a,p,nb(b,k),c][j])^2
//   out = sum_b pos_sum[b]/neg_sum[b]          (the 1/(C*N) mean factors cancel)
//
// Three uniform kernels:
//  1) sort_both: per block, packed-fp16 bitonic sort of BOTH the S-row and the
//     T-row (two independent chains -> 2x ILP in the latency-exposed passes);
//     writes packed sorted rows to ws.
//  2) diff_rows: pure streaming diff (sortT vs sortS[pos] + 2 neg rows),
//     v_dot2_f32_f16 accumulate, block reduce, per-row partial. NO atomics.
//  3) finalize: single block double-precision reduction of 4096x2 partials.

typedef unsigned int u32;
typedef __fp16 f16x2 __attribute__((ext_vector_type(2)));

constexpr int N     = 4096;
constexpr int NTH   = 256;
constexpr int CDIM  = 128;
constexpr int BDIM  = 4;
constexpr int KNEG  = 2;
constexpr int ROWS  = 4096;
constexpr int HALF  = 2048;
constexpr int LSTRW = 20;      // u32 per thread-row in LDS (80B, 16B-aligned)
constexpr int ROWW  = N / 2;   // 2048 packed words per row

// ---------- packed fp16 primitives ----------
__device__ inline u32 pk_min(u32 a, u32 b) {
  u32 d; asm("v_pk_min_f16 %0, %1, %2" : "=v"(d) : "v"(a), "v"(b)); return d;
}
__device__ inline u32 pk_max(u32 a, u32 b) {
  u32 d; asm("v_pk_max_f16 %0, %1, %2" : "=v"(d) : "v"(a), "v"(b)); return d;
}
__device__ inline u32 pk_min_swap(u32 a) {  // d.lo = min(a.lo, a.hi)
  u32 d; asm("v_pk_min_f16 %0, %1, %1 op_sel:[0,1] op_sel_hi:[1,0]" : "=v"(d) : "v"(a)); return d;
}
__device__ inline u32 pk_max_swap(u32 a) {  // d.hi = max(a.lo, a.hi)
  u32 d; asm("v_pk_max_f16 %0, %1, %1 op_sel:[0,1] op_sel_hi:[1,0]" : "=v"(d) : "v"(a)); return d;
}
__device__ inline u32 pk_sub(u32 a, u32 b) {   // a - b per half
  u32 d; asm("v_pk_add_f16 %0, %1, %2 neg_lo:[0,1] neg_hi:[0,1]" : "=v"(d) : "v"(a), "v"(b)); return d;
}
__device__ inline float dot2acc(u32 d, float acc) {  // acc += d.lo^2 + d.hi^2
  asm("v_dot2_f32_f16 %0, %1, %2, %0" : "+v"(acc) : "v"(d), "v"(d)); return acc;
}

__device__ inline void pk_cswap(u32& a, u32& b) {
  const u32 mn = pk_min(a, b), mx = pk_max(a, b);
  a = mn; b = mx;
}
__device__ inline u32 pk_sort_pair(u32 a) {   // lo' = min(halves), hi' = max
  const u32 mn = pk_min_swap(a);
  const u32 mx = pk_max_swap(a);
  return (mx & 0xFFFF0000u) | (mn & 0x0000FFFFu);
}

// ---------- f32 pre-stage (k <= 8) ----------
__device__ inline void cswap_asc(float& a, float& b) {
  const float lo = fminf(a, b), hi = fmaxf(a, b);
  a = lo; b = hi;
}
template<int K, int J>
__device__ inline void local_pass(float v[16]) {
  #pragma unroll
  for (int m = 0; m < 16; ++m)
    if ((m & J) == 0) {
      if ((m & K) == 0) cswap_asc(v[m], v[m ^ J]);
      else              cswap_asc(v[m ^ J], v[m]);
    }
}

// ---------- cross-lane exchanges on packed words ----------
// DPP ctrls: 0xB1=quad xor1, 0x4E=quad xor2, 0x1B=quad xor3,
//            0x141=row_half_mirror (xor7), 0x128=row_ror:8 (xor8)
template<int CTRL>
__device__ inline u32 dpp_u(u32 x) {
  return (u32)__builtin_amdgcn_update_dpp((int)x, (int)x, CTRL, 0xF, 0xF, false);
}

template<int TM>   // TM in {1,2,4,8}: per-lane keep-min = ((t&TM)==0)
__device__ inline void pass_small_pk(u32 h[8], int t) {
  const bool km = ((t & TM) == 0);
  u32 o[8];
  #pragma unroll
  for (int p = 0; p < 8; ++p) {
    if constexpr (TM == 1)      o[p] = dpp_u<0xB1>(h[p]);
    else if constexpr (TM == 2) o[p] = dpp_u<0x4E>(h[p]);
    else if constexpr (TM == 4) o[p] = dpp_u<0x141>(dpp_u<0x1B>(h[p]));
    else                        o[p] = dpp_u<0x128>(h[p]);
  }
  #pragma unroll
  for (int p = 0; p < 8; ++p) {
    const u32 mn = pk_min(h[p], o[p]), mx = pk_max(h[p], o[p]);
    h[p] = km ? mn : mx;
  }
}

__device__ inline void swap32u(u32& a, u32& b) {
  asm("v_permlane32_swap_b32 %0, %1" : "+v"(a), "+v"(b));
}
__device__ inline void swap16u(u32& a, u32& b) {
  asm("v_permlane16_swap_b32 %0, %1" : "+v"(a), "+v"(b));
}
template<bool IS32>
__device__ inline void pass_perm_pk(u32 h[8]) {
  #pragma unroll
  for (int q = 0; q < 4; ++q) {
    u32 a = h[2*q], b = h[2*q + 1];
    if constexpr (IS32) swap32u(a, b); else swap16u(a, b);
    u32 mn = pk_min(a, b);
    u32 mx = pk_max(a, b);
    if constexpr (IS32) swap32u(mn, mx); else swap16u(mn, mx);
    h[2*q] = mn; h[2*q + 1] = mx;
  }
}

// one row's LDS exchange (thread-xor 64/128); caller manages barriers
template<int TM>
__device__ inline void lds_xchg_row(u32 h[8], u32* buf, int t) {
  uint4* wp = (uint4*)(buf + t * LSTRW);
  wp[0] = make_uint4(h[0], h[1], h[2], h[3]);
  wp[1] = make_uint4(h[4], h[5], h[6], h[7]);
  __syncthreads();
  const uint4* rp = (const uint4*)(buf + (t ^ TM) * LSTRW);
  const uint4 x0 = rp[0], x1 = rp[1];
  if (t & TM) {
    h[0] = pk_max(h[0], x0.x); h[1] = pk_max(h[1], x0.y);
    h[2] = pk_max(h[2], x0.z); h[3] = pk_max(h[3], x0.w);
    h[4] = pk_max(h[4], x1.x); h[5] = pk_max(h[5], x1.y);
    h[6] = pk_max(h[6], x1.z); h[7] = pk_max(h[7], x1.w);
  } else {
    h[0] = pk_min(h[0], x0.x); h[1] = pk_min(h[1], x0.y);
    h[2] = pk_min(h[2], x0.z); h[3] = pk_min(h[3], x0.w);
    h[4] = pk_min(h[4], x1.x); h[5] = pk_min(h[5], x1.y);
    h[6] = pk_min(h[6], x1.z); h[7] = pk_min(h[7], x1.w);
  }
}

// both rows, sharing one LDS buffer sequentially (keeps LDS at 1 row's size)
template<int TM>
__device__ inline void pass_lds_pk2(u32 hA[8], u32 hB[8], u32* buf, int t) {
  __syncthreads();                 // protect prior reads of buf
  lds_xchg_row<TM>(hA, buf, t);
  __syncthreads();                 // A's reads done before overwrite
  lds_xchg_row<TM>(hB, buf, t);
}

template<int K, int J>
__device__ inline void cross_pk2(u32 hA[8], u32 hB[8], u32* buf, int t) {
  if constexpr (J >= 16) {
    constexpr int TM = J >> 4;
    if constexpr (TM >= 64)      pass_lds_pk2<TM>(hA, hB, buf, t);
    else if constexpr (TM == 32) { pass_perm_pk<true>(hA);  pass_perm_pk<true>(hB); }
    else if constexpr (TM == 16) { pass_perm_pk<false>(hA); pass_perm_pk<false>(hB); }
    else                         { pass_small_pk<TM>(hA, t); pass_small_pk<TM>(hB, t); }
    cross_pk2<K, (J >> 1)>(hA, hB, buf, t);
  }
}

// in-register ascending tail: j = 8 (within-word), then 4, 2, 1 (cross-word)
__device__ inline void tail_pk(u32 h[8]) {
  #pragma unroll
  for (int p = 0; p < 8; ++p) h[p] = pk_sort_pair(h[p]);
  pk_cswap(h[0], h[4]); pk_cswap(h[1], h[5]); pk_cswap(h[2], h[6]); pk_cswap(h[3], h[7]);
  pk_cswap(h[0], h[2]); pk_cswap(h[1], h[3]); pk_cswap(h[4], h[6]); pk_cswap(h[5], h[7]);
  pk_cswap(h[0], h[1]); pk_cswap(h[2], h[3]); pk_cswap(h[4], h[5]); pk_cswap(h[6], h[7]);
}

__device__ inline void flip_pk(u32 h[8], u32 f) {
  #pragma unroll
  for (int p = 0; p < 8; ++p) h[p] ^= f;
}

template<int K>
__device__ inline void stage_pk2(u32 hA[8], u32 hB[8], u32* buf, int t, u32& cur) {
  const u32 f = (t & (K >> 4)) ? 0x80008000u : 0u;
  flip_pk(hA, f ^ cur); flip_pk(hB, f ^ cur);
  cur = f;
  cross_pk2<K, (K >> 1)>(hA, hB, buf, t);
  tail_pk(hA); tail_pk(hB);
}

// load 16 f32, pre-sort k<=8 in f32, pack to 8 fp16x2 words (m, m+8)
__device__ inline void load_prestage_pack(const float* __restrict__ src,
                                          u32 h[8], int t) {
  float v[16];
  const float4* s4 = (const float4*)src;
  #pragma unroll
  for (int q = 0; q < 4; ++q) {
    const float4 x = s4[t * 4 + q];
    v[q*4+0] = x.x; v[q*4+1] = x.y; v[q*4+2] = x.z; v[q*4+3] = x.w;
  }
  local_pass<2, 1>(v);
  local_pass<4, 2>(v); local_pass<4, 1>(v);
  local_pass<8, 4>(v); local_pass<8, 2>(v); local_pass<8, 1>(v);
  #pragma unroll
  for (int p = 0; p < 8; ++p) {
    const f16x2 pk = __builtin_amdgcn_cvt_pkrtz(v[p], v[p + 8]);
    h[p] = __builtin_bit_cast(u32, pk);
  }
}

__device__ inline void sort4096_pk2(u32 hA[8], u32 hB[8], u32* buf, int t) {
  u32 cur = 0;
  stage_pk2<16>(hA, hB, buf, t, cur);
  stage_pk2<32>(hA, hB, buf, t, cur);
  stage_pk2<64>(hA, hB, buf, t, cur);
  stage_pk2<128>(hA, hB, buf, t, cur);
  stage_pk2<256>(hA, hB, buf, t, cur);
  stage_pk2<512>(hA, hB, buf, t, cur);
  stage_pk2<1024>(hA, hB, buf, t, cur);
  stage_pk2<2048>(hA, hB, buf, t, cur);
  stage_pk2<4096>(hA, hB, buf, t, cur);
  // cur == 0 for all t<256 at the end; no final unflip needed
}

__device__ inline void store_row(u32* __restrict__ dst, const u32 h[8], int t) {
  uint4* d4 = (uint4*)dst;
  d4[t*2]     = make_uint4(h[0], h[1], h[2], h[3]);
  d4[t*2 + 1] = make_uint4(h[4], h[5], h[6], h[7]);
}

// kernel 1: sort the S-row and T-row of index r (two chains per wave)
__global__ __launch_bounds__(NTH)
void sort_both(const float* __restrict__ sE, const float* __restrict__ sS,
               const float* __restrict__ tE, const float* __restrict__ tS,
               u32* __restrict__ Ss, u32* __restrict__ Ts) {
  __shared__ u32 buf[NTH * LSTRW];
  const int t = threadIdx.x, r = blockIdx.x;
  const float* srcS = (r < HALF) ? sE + (size_t)r * N : sS + (size_t)(r - HALF) * N;
  const float* srcT = (r < HALF) ? tE + (size_t)r * N : tS + (size_t)(r - HALF) * N;
  u32 hA[8], hB[8];
  load_prestage_pack(srcS, hA, t);
  load_prestage_pack(srcT, hB, t);
  sort4096_pk2(hA, hB, buf, t);
  store_row(Ss + (size_t)r * ROWW, hA, t);
  store_row(Ts + (size_t)r * ROWW, hB, t);
}

// kernel 2: streaming diff; per-row partials, no atomics
__global__ __launch_bounds__(NTH)
void diff_rows(const u32* __restrict__ Ss, const u32* __restrict__ Ts,
               const int* __restrict__ neg_idx, float2* __restrict__ partial) {
  __shared__ float red[2][4];
  const int t = threadIdx.x, r = blockIdx.x;

  const uint4* tp = (const uint4*)(Ts + (size_t)r * ROWW);
  const uint4 h0 = tp[t*2], h1 = tp[t*2 + 1];

  // r = ((ap)*B + b)*C + c
  const int c  = r & (CDIM - 1);
  const int b  = (r / CDIM) & (BDIM - 1);
  const int ap = r / (CDIM * BDIM);

  float posp = 0.f, negp = 0.f;
  {
    const uint4* vp = (const uint4*)(Ss + (size_t)r * ROWW);
    const uint4 w0 = vp[t*2], w1 = vp[t*2 + 1];
    posp = dot2acc(pk_sub(h0.x, w0.x), posp);
    posp = dot2acc(pk_sub(h0.y, w0.y), posp);
    posp = dot2acc(pk_sub(h0.z, w0.z), posp);
    posp = dot2acc(pk_sub(h0.w, w0.w), posp);
    posp = dot2acc(pk_sub(h1.x, w1.x), posp);
    posp = dot2acc(pk_sub(h1.y, w1.y), posp);
    posp = dot2acc(pk_sub(h1.z, w1.z), posp);
    posp = dot2acc(pk_sub(h1.w, w1.w), posp);
  }
  #pragma unroll
  for (int k = 0; k < KNEG; ++k) {
    const int nb = neg_idx[b * KNEG + k];
    const uint4* vp = (const uint4*)(Ss + ((size_t)(ap * BDIM + nb) * CDIM + c) * ROWW);
    const uint4 w0 = vp[t*2], w1 = vp[t*2 + 1];
    negp = dot2acc(pk_sub(h0.x, w0.x), negp);
    negp = dot2acc(pk_sub(h0.y, w0.y), negp);
    negp = dot2acc(pk_sub(h0.z, w0.z), negp);
    negp = dot2acc(pk_sub(h0.w, w0.w), negp);
    negp = dot2acc(pk_sub(h1.x, w1.x), negp);
    negp = dot2acc(pk_sub(h1.y, w1.y), negp);
    negp = dot2acc(pk_sub(h1.z, w1.z), negp);
    negp = dot2acc(pk_sub(h1.w, w1.w), negp);
  }

  #pragma unroll
  for (int off = 32; off > 0; off >>= 1) {
    posp += __shfl_down(posp, off, 64);
    negp += __shfl_down(negp, off, 64);
  }
  const int wid = t >> 6, lane = t & 63;
  if (lane == 0) { red[0][wid] = posp; red[1][wid] = negp; }
  __syncthreads();
  if (t == 0) {
    const float pt = red[0][0] + red[0][1] + red[0][2] + red[0][3];
    const float nt = red[1][0] + red[1][1] + red[1][2] + red[1][3];
    partial[r] = make_float2(pt, nt);
  }
}

// kernel 3: single-block reduction of 4096 partials, keyed by b
__global__ __launch_bounds__(NTH)
void finalize(const float2* __restrict__ partial, float* __restrict__ out) {
  __shared__ double rp[4], rn[4];
  const int t = threadIdx.x;
  const int wid = t >> 6, lane = t & 63;
  double res = 0.0;
  #pragma unroll
  for (int b = 0; b < BDIM; ++b) {
    double p = 0.0, n = 0.0;
    for (int idx = t; idx < 1024; idx += NTH) {     // 8 ap-chunks x 128 c
      const int a = idx >> 7, c = idx & 127;
      const float2 v = partial[a * 512 + b * 128 + c];
      p += (double)v.x; n += (double)v.y;
    }
    #pragma unroll
    for (int off = 32; off > 0; off >>= 1) {
      p += __shfl_down(p, off, 64);
      n += __shfl_down(n, off, 64);
    }
    if (lane == 0) { rp[wid] = p; rn[wid] = n; }
    __syncthreads();
    if (t == 0) {
      const double P = rp[0] + rp[1] + rp[2] + rp[3];
      const double Nn = rn[0] + rn[1] + rn[2] + rn[3];
      res += P / Nn;
    }
    __syncthreads();   // rp/rn reused next b
  }
  if (t == 0) out[0] = (float)res;
}

extern "C" void kernel_launch(void* const* d_in, const int* in_sizes, int n_in,
                              void* d_out, int out_size, void* d_ws, size_t ws_size,
                              hipStream_t stream) {
  const float* style_E = (const float*)d_in[0];
  const float* style_S = (const float*)d_in[1];
  const float* trans_E = (const float*)d_in[2];
  const float* trans_S = (const float*)d_in[3];
  const int*   neg_idx = (const int*)d_in[4];

  // ws layout: Ss packed (33.5MB), Ts packed (33.5MB), partial (32KB)
  u32*    Ss      = (u32*)d_ws;
  u32*    Ts      = Ss + (size_t)ROWS * ROWW;
  float2* partial = (float2*)(Ts + (size_t)ROWS * ROWW);

  sort_both<<<ROWS, NTH, 0, stream>>>(style_E, style_S, trans_E, trans_S, Ss, Ts);
  diff_rows<<<ROWS, NTH, 0, stream>>>(Ss, Ts, neg_idx, partial);
  finalize<<<1, NTH, 0, stream>>>(partial, (float*)d_out);
}

// Round 10
// 124.698 us; speedup vs baseline: 1.9415x; 1.0156x over previous
//
#include <hip/hip_runtime.h>

// EFDM loss — reduced form:
//   pos_sum[b]  = sum over (a,p,c,j) of (sortT[a,p,b,c][j] - sortS[a,p,b,c][j])^2
//   neg_sum[b]  = sum over (a,p,k,c,j) of (sortT[a,p,b,c][j] - sortS[a,p,nb(b,k),c][j])^2
//   out = sum_b pos_sum[b]/neg_sum[b]          (the 1/(C*N) mean factors cancel)
//
// Three kernels:
//  1) sort_one: 8192 blocks, ONE row per block (single packed-fp16 chain —
//     the R8-proven shape; dual-chain fusion regressed via register pressure).
//     Blocks [0,4096) sort S rows, [4096,8192) sort T rows.
//  2) diff_rows: pure streaming diff (sortT vs sortS[pos] + 2 neg rows),
//     v_dot2_f32_f16 accumulate, block reduce, per-row partial. NO atomics.
//  3) finalize: single block double-precision reduction of 4096x2 partials.

typedef unsigned int u32;
typedef __fp16 f16x2 __attribute__((ext_vector_type(2)));

constexpr int N     = 4096;
constexpr int NTH   = 256;
constexpr int CDIM  = 128;
constexpr int BDIM  = 4;
constexpr int KNEG  = 2;
constexpr int ROWS  = 4096;
constexpr int HALF  = 2048;
constexpr int LSTRW = 20;      // u32 per thread-row in LDS (80B, 16B-aligned; stride
                               // 20 dwords -> all 32 banks covered, conflict-free b128)
constexpr int ROWW  = N / 2;   // 2048 packed words per row

// ---------- packed fp16 primitives ----------
__device__ inline u32 pk_min(u32 a, u32 b) {
  u32 d; asm("v_pk_min_f16 %0, %1, %2" : "=v"(d) : "v"(a), "v"(b)); return d;
}
__device__ inline u32 pk_max(u32 a, u32 b) {
  u32 d; asm("v_pk_max_f16 %0, %1, %2" : "=v"(d) : "v"(a), "v"(b)); return d;
}
__device__ inline u32 pk_min_swap(u32 a) {  // d.lo = min(a.lo, a.hi)
  u32 d; asm("v_pk_min_f16 %0, %1, %1 op_sel:[0,1] op_sel_hi:[1,0]" : "=v"(d) : "v"(a)); return d;
}
__device__ inline u32 pk_max_swap(u32 a) {  // d.hi = max(a.lo, a.hi)
  u32 d; asm("v_pk_max_f16 %0, %1, %1 op_sel:[0,1] op_sel_hi:[1,0]" : "=v"(d) : "v"(a)); return d;
}
__device__ inline u32 pk_sub(u32 a, u32 b) {   // a - b per half
  u32 d; asm("v_pk_add_f16 %0, %1, %2 neg_lo:[0,1] neg_hi:[0,1]" : "=v"(d) : "v"(a), "v"(b)); return d;
}
__device__ inline float dot2acc(u32 d, float acc) {  // acc += d.lo^2 + d.hi^2
  asm("v_dot2_f32_f16 %0, %1, %2, %0" : "+v"(acc) : "v"(d), "v"(d)); return acc;
}

__device__ inline void pk_cswap(u32& a, u32& b) {
  const u32 mn = pk_min(a, b), mx = pk_max(a, b);
  a = mn; b = mx;
}
__device__ inline u32 pk_sort_pair(u32 a) {   // lo' = min(halves), hi' = max
  const u32 mn = pk_min_swap(a);
  const u32 mx = pk_max_swap(a);
  return (mx & 0xFFFF0000u) | (mn & 0x0000FFFFu);
}

// ---------- f32 pre-stage (k <= 8) ----------
__device__ inline void cswap_asc(float& a, float& b) {
  const float lo = fminf(a, b), hi = fmaxf(a, b);
  a = lo; b = hi;
}
template<int K, int J>
__device__ inline void local_pass(float v[16]) {
  #pragma unroll
  for (int m = 0; m < 16; ++m)
    if ((m & J) == 0) {
      if ((m & K) == 0) cswap_asc(v[m], v[m ^ J]);
      else              cswap_asc(v[m ^ J], v[m]);
    }
}

// ---------- cross-lane exchanges on packed words ----------
// DPP ctrls: 0xB1=quad xor1, 0x4E=quad xor2, 0x1B=quad xor3,
//            0x141=row_half_mirror (xor7), 0x128=row_ror:8 (xor8)
template<int CTRL>
__device__ inline u32 dpp_u(u32 x) {
  return (u32)__builtin_amdgcn_update_dpp((int)x, (int)x, CTRL, 0xF, 0xF, false);
}

template<int TM>   // TM in {1,2,4,8}: per-lane keep-min = ((t&TM)==0)
__device__ inline void pass_small_pk(u32 h[8], int t) {
  const bool km = ((t & TM) == 0);
  u32 o[8];
  #pragma unroll
  for (int p = 0; p < 8; ++p) {
    if constexpr (TM == 1)      o[p] = dpp_u<0xB1>(h[p]);
    else if constexpr (TM == 2) o[p] = dpp_u<0x4E>(h[p]);
    else if constexpr (TM == 4) o[p] = dpp_u<0x141>(dpp_u<0x1B>(h[p]));
    else                        o[p] = dpp_u<0x128>(h[p]);
  }
  #pragma unroll
  for (int p = 0; p < 8; ++p) {
    const u32 mn = pk_min(h[p], o[p]), mx = pk_max(h[p], o[p]);
    h[p] = km ? mn : mx;
  }
}

__device__ inline void swap32u(u32& a, u32& b) {
  asm("v_permlane32_swap_b32 %0, %1" : "+v"(a), "+v"(b));
}
__device__ inline void swap16u(u32& a, u32& b) {
  asm("v_permlane16_swap_b32 %0, %1" : "+v"(a), "+v"(b));
}
template<bool IS32>
__device__ inline void pass_perm_pk(u32 h[8]) {
  #pragma unroll
  for (int q = 0; q < 4; ++q) {
    u32 a = h[2*q], b = h[2*q + 1];
    if constexpr (IS32) swap32u(a, b); else swap16u(a, b);
    u32 mn = pk_min(a, b);
    u32 mx = pk_max(a, b);
    if constexpr (IS32) swap32u(mn, mx); else swap16u(mn, mx);
    h[2*q] = mn; h[2*q + 1] = mx;
  }
}

// thread-xor 64/128 via LDS; keep decision wave-uniform
template<int TM>
__device__ inline void pass_lds_pk(u32 h[8], u32* buf, int t) {
  __syncthreads();   // protect prior reads of buf
  uint4* wp = (uint4*)(buf + t * LSTRW);
  wp[0] = make_uint4(h[0], h[1], h[2], h[3]);
  wp[1] = make_uint4(h[4], h[5], h[6], h[7]);
  __syncthreads();
  const uint4* rp = (const uint4*)(buf + (t ^ TM) * LSTRW);
  const uint4 x0 = rp[0], x1 = rp[1];
  if (t & TM) {
    h[0] = pk_max(h[0], x0.x); h[1] = pk_max(h[1], x0.y);
    h[2] = pk_max(h[2], x0.z); h[3] = pk_max(h[3], x0.w);
    h[4] = pk_max(h[4], x1.x); h[5] = pk_max(h[5], x1.y);
    h[6] = pk_max(h[6], x1.z); h[7] = pk_max(h[7], x1.w);
  } else {
    h[0] = pk_min(h[0], x0.x); h[1] = pk_min(h[1], x0.y);
    h[2] = pk_min(h[2], x0.z); h[3] = pk_min(h[3], x0.w);
    h[4] = pk_min(h[4], x1.x); h[5] = pk_min(h[5], x1.y);
    h[6] = pk_min(h[6], x1.z); h[7] = pk_min(h[7], x1.w);
  }
}

template<int K, int J>
__device__ inline void cross_pk(u32 h[8], u32* buf, int t) {
  if constexpr (J >= 16) {
    constexpr int TM = J >> 4;
    if constexpr (TM >= 64)      pass_lds_pk<TM>(h, buf, t);
    else if constexpr (TM == 32) pass_perm_pk<true>(h);
    else if constexpr (TM == 16) pass_perm_pk<false>(h);
    else                         pass_small_pk<TM>(h, t);
    cross_pk<K, (J >> 1)>(h, buf, t);
  }
}

// in-register ascending tail: j = 8 (within-word), then 4, 2, 1 (cross-word)
__device__ inline void tail_pk(u32 h[8]) {
  #pragma unroll
  for (int p = 0; p < 8; ++p) h[p] = pk_sort_pair(h[p]);
  pk_cswap(h[0], h[4]); pk_cswap(h[1], h[5]); pk_cswap(h[2], h[6]); pk_cswap(h[3], h[7]);
  pk_cswap(h[0], h[2]); pk_cswap(h[1], h[3]); pk_cswap(h[4], h[6]); pk_cswap(h[5], h[7]);
  pk_cswap(h[0], h[1]); pk_cswap(h[2], h[3]); pk_cswap(h[4], h[5]); pk_cswap(h[6], h[7]);
}

__device__ inline void flip_pk(u32 h[8], u32 f) {
  #pragma unroll
  for (int p = 0; p < 8; ++p) h[p] ^= f;
}

template<int K>
__device__ inline void stage_pk(u32 h[8], u32* buf, int t, u32& cur) {
  const u32 f = (t & (K >> 4)) ? 0x80008000u : 0u;
  flip_pk(h, f ^ cur);
  cur = f;
  cross_pk<K, (K >> 1)>(h, buf, t);
  tail_pk(h);
}

// load 16 f32, pre-sort k<=8 in f32, pack to 8 fp16x2 words (m, m+8)
__device__ inline void load_prestage_pack(const float* __restrict__ src,
                                          u32 h[8], int t) {
  float v[16];
  const float4* s4 = (const float4*)src;
  #pragma unroll
  for (int q = 0; q < 4; ++q) {
    const float4 x = s4[t * 4 + q];
    v[q*4+0] = x.x; v[q*4+1] = x.y; v[q*4+2] = x.z; v[q*4+3] = x.w;
  }
  local_pass<2, 1>(v);
  local_pass<4, 2>(v); local_pass<4, 1>(v);
  local_pass<8, 4>(v); local_pass<8, 2>(v); local_pass<8, 1>(v);
  #pragma unroll
  for (int p = 0; p < 8; ++p) {
    const f16x2 pk = __builtin_amdgcn_cvt_pkrtz(v[p], v[p + 8]);
    h[p] = __builtin_bit_cast(u32, pk);
  }
}

__device__ inline void sort4096_pk(u32 h[8], u32* buf, int t) {
  u32 cur = 0;
  stage_pk<16>(h, buf, t, cur);
  stage_pk<32>(h, buf, t, cur);
  stage_pk<64>(h, buf, t, cur);
  stage_pk<128>(h, buf, t, cur);
  stage_pk<256>(h, buf, t, cur);
  stage_pk<512>(h, buf, t, cur);
  stage_pk<1024>(h, buf, t, cur);
  stage_pk<2048>(h, buf, t, cur);
  stage_pk<4096>(h, buf, t, cur);
  // cur == 0 for all t<256 at the end; no final unflip needed
}

__device__ inline void store_row(u32* __restrict__ dst, const u32 h[8], int t) {
  uint4* d4 = (uint4*)dst;
  d4[t*2]     = make_uint4(h[0], h[1], h[2], h[3]);
  d4[t*2 + 1] = make_uint4(h[4], h[5], h[6], h[7]);
}

// kernel 1: 8192 blocks, one row each. [0,ROWS)=S rows, [ROWS,2*ROWS)=T rows.
__global__ __launch_bounds__(NTH)
void sort_one(const float* __restrict__ sE, const float* __restrict__ sS,
              const float* __restrict__ tE, const float* __restrict__ tS,
              u32* __restrict__ Ss, u32* __restrict__ Ts) {
  __shared__ u32 buf[NTH * LSTRW];
  const int t = threadIdx.x;
  int r = blockIdx.x;
  const float* src;
  u32* dst;
  if (r < ROWS) {
    src = (r < HALF) ? sE + (size_t)r * N : sS + (size_t)(r - HALF) * N;
    dst = Ss + (size_t)r * ROWW;
  } else {
    r -= ROWS;
    src = (r < HALF) ? tE + (size_t)r * N : tS + (size_t)(r - HALF) * N;
    dst = Ts + (size_t)r * ROWW;
  }
  u32 h[8];
  load_prestage_pack(src, h, t);
  sort4096_pk(h, buf, t);
  store_row(dst, h, t);
}

// kernel 2: streaming diff; per-row partials, no atomics
__global__ __launch_bounds__(NTH)
void diff_rows(const u32* __restrict__ Ss, const u32* __restrict__ Ts,
               const int* __restrict__ neg_idx, float2* __restrict__ partial) {
  __shared__ float red[2][4];
  const int t = threadIdx.x, r = blockIdx.x;

  const uint4* tp = (const uint4*)(Ts + (size_t)r * ROWW);
  const uint4 h0 = tp[t*2], h1 = tp[t*2 + 1];

  // r = ((ap)*B + b)*C + c
  const int c  = r & (CDIM - 1);
  const int b  = (r / CDIM) & (BDIM - 1);
  const int ap = r / (CDIM * BDIM);

  float posp = 0.f, negp = 0.f;
  {
    const uint4* vp = (const uint4*)(Ss + (size_t)r * ROWW);
    const uint4 w0 = vp[t*2], w1 = vp[t*2 + 1];
    posp = dot2acc(pk_sub(h0.x, w0.x), posp);
    posp = dot2acc(pk_sub(h0.y, w0.y), posp);
    posp = dot2acc(pk_sub(h0.z, w0.z), posp);
    posp = dot2acc(pk_sub(h0.w, w0.w), posp);
    posp = dot2acc(pk_sub(h1.x, w1.x), posp);
    posp = dot2acc(pk_sub(h1.y, w1.y), posp);
    posp = dot2acc(pk_sub(h1.z, w1.z), posp);
    posp = dot2acc(pk_sub(h1.w, w1.w), posp);
  }
  #pragma unroll
  for (int k = 0; k < KNEG; ++k) {
    const int nb = neg_idx[b * KNEG + k];
    const uint4* vp = (const uint4*)(Ss + ((size_t)(ap * BDIM + nb) * CDIM + c) * ROWW);
    const uint4 w0 = vp[t*2], w1 = vp[t*2 + 1];
    negp = dot2acc(pk_sub(h0.x, w0.x), negp);
    negp = dot2acc(pk_sub(h0.y, w0.y), negp);
    negp = dot2acc(pk_sub(h0.z, w0.z), negp);
    negp = dot2acc(pk_sub(h0.w, w0.w), negp);
    negp = dot2acc(pk_sub(h1.x, w1.x), negp);
    negp = dot2acc(pk_sub(h1.y, w1.y), negp);
    negp = dot2acc(pk_sub(h1.z, w1.z), negp);
    negp = dot2acc(pk_sub(h1.w, w1.w), negp);
  }

  #pragma unroll
  for (int off = 32; off > 0; off >>= 1) {
    posp += __shfl_down(posp, off, 64);
    negp += __shfl_down(negp, off, 64);
  }
  const int wid = t >> 6, lane = t & 63;
  if (lane == 0) { red[0][wid] = posp; red[1][wid] = negp; }
  __syncthreads();
  if (t == 0) {
    const float pt = red[0][0] + red[0][1] + red[0][2] + red[0][3];
    const float nt = red[1][0] + red[1][1] + red[1][2] + red[1][3];
    partial[r] = make_float2(pt, nt);
  }
}

// kernel 3: single-block reduction of 4096 partials, keyed by b
__global__ __launch_bounds__(NTH)
void finalize(const float2* __restrict__ partial, float* __restrict__ out) {
  __shared__ double rp[4], rn[4];
  const int t = threadIdx.x;
  const int wid = t >> 6, lane = t & 63;
  double res = 0.0;
  #pragma unroll
  for (int b = 0; b < BDIM; ++b) {
    double p = 0.0, n = 0.0;
    for (int idx = t; idx < 1024; idx += NTH) {     // 8 ap-chunks x 128 c
      const int a = idx >> 7, c = idx & 127;
      const float2 v = partial[a * 512 + b * 128 + c];
      p += (double)v.x; n += (double)v.y;
    }
    #pragma unroll
    for (int off = 32; off > 0; off >>= 1) {
      p += __shfl_down(p, off, 64);
      n += __shfl_down(n, off, 64);
    }
    if (lane == 0) { rp[wid] = p; rn[wid] = n; }
    __syncthreads();
    if (t == 0) {
      const double P = rp[0] + rp[1] + rp[2] + rp[3];
      const double Nn = rn[0] + rn[1] + rn[2] + rn[3];
      res += P / Nn;
    }
    __syncthreads();   // rp/rn reused next b
  }
  if (t == 0) out[0] = (float)res;
}

extern "C" void kernel_launch(void* const* d_in, const int* in_sizes, int n_in,
                              void* d_out, int out_size, void* d_ws, size_t ws_size,
                              hipStream_t stream) {
  const float* style_E = (const float*)d_in[0];
  const float* style_S = (const float*)d_in[1];
  const float* trans_E = (const float*)d_in[2];
  const float* trans_S = (const float*)d_in[3];
  const int*   neg_idx = (const int*)d_in[4];

  // ws layout: Ss packed (16.8MB), Ts packed (16.8MB), partial (32KB)
  u32*    Ss      = (u32*)d_ws;
  u32*    Ts      = Ss + (size_t)ROWS * ROWW;
  float2* partial = (float2*)(Ts + (size_t)ROWS * ROWW);

  sort_one<<<2 * ROWS, NTH, 0, stream>>>(style_E, style_S, trans_E, trans_S, Ss, Ts);
  diff_rows<<<ROWS, NTH, 0, stream>>>(Ss, Ts, neg_idx, partial);
  finalize<<<1, NTH, 0, stream>>>(partial, (float*)d_out);
}

// Round 11
// 118.974 us; speedup vs baseline: 2.0349x; 1.0481x over previous
//
#include <hip/hip_runtime.h>

// EFDM loss — reduced form:
//   pos_sum[b]  = sum over (a,p,c,j) of (sortT[a,p,b,c][j] - sortS[a,p,b,c][j])^2
//   neg_sum[b]  = sum over (a,p,k,c,j) of (sortT[a,p,b,c][j] - sortS[a,p,nb(b,k),c][j])^2
//   out = sum_b pos_sum[b]/neg_sum[b]          (the 1/(C*N) mean factors cancel)
//
// Kernel 1 (sort_one): 8192 blocks, one row per block. Packed-fp16 register
// bitonic, 16 elems/thread as 8 words (m, m+8). New this round:
//  - polarized DPP passes: h stored sign-multiplied by sigma_TM(t); exchange =
//    pk_min(h, -dpp(h)) with the negate fused into v_pk_min_f16 neg modifiers
//    (2 ops/word/pass instead of 4); polarity transitions are XOR masks, and
//    the entry mask is folded into the stage flip for K<=256.
//  - packed pre-stage (k=2,4,8 via pk_cswap; k=8 hi-half direction via a
//    hi-sign flip absorbed into cur = 0x80000000).
//  - coalesced SoA stores (d4[t], d4[NTH+t] -> contiguous 1KB per instruction)
//  - LDS exchange buffer 16896B with bank-spread slots -> 8 blocks/CU.
// Kernel 2 (diff_rows): streaming diff, per-row partials, no atomics.
// Kernel 3 (finalize): one-block double reduction.

typedef unsigned int u32;
typedef __fp16 f16x2 __attribute__((ext_vector_type(2)));

constexpr int N     = 4096;
constexpr int NTH   = 256;
constexpr int CDIM  = 128;
constexpr int BDIM  = 4;
constexpr int KNEG  = 2;
constexpr int ROWS  = 4096;
constexpr int HALF  = 2048;
constexpr int ROWW  = N / 2;   // 2048 packed words per row

// LDS slot (in words): 16 words/thread + 4-word shift per 8 threads.
// 16B-aligned; spreads the 64 lanes of a b128 access evenly over all 8
// bank-quads (8 lanes/quad) -> conflict-free like the measured stride-20.
__device__ inline int lslot(int t) { return t * 16 + ((t >> 3) << 2); }
constexpr int LDSW = 4224;     // 16896 B > lslot(255)+8 = 4212

// ---------- packed fp16 primitives ----------
__device__ inline u32 pk_min(u32 a, u32 b) {
  u32 d; asm("v_pk_min_f16 %0, %1, %2" : "=v"(d) : "v"(a), "v"(b)); return d;
}
__device__ inline u32 pk_max(u32 a, u32 b) {
  u32 d; asm("v_pk_max_f16 %0, %1, %2" : "=v"(d) : "v"(a), "v"(b)); return d;
}
__device__ inline u32 pk_min_negb(u32 a, u32 b) {   // min(a, -b) per half
  u32 d; asm("v_pk_min_f16 %0, %1, %2 neg_lo:[0,1] neg_hi:[0,1]" : "=v"(d) : "v"(a), "v"(b)); return d;
}
__device__ inline u32 pk_min_swap(u32 a) {  // d.lo = min(a.lo, a.hi)
  u32 d; asm("v_pk_min_f16 %0, %1, %1 op_sel:[0,1] op_sel_hi:[1,0]" : "=v"(d) : "v"(a)); return d;
}
__device__ inline u32 pk_max_swap(u32 a) {  // d.hi = max(a.lo, a.hi)
  u32 d; asm("v_pk_max_f16 %0, %1, %1 op_sel:[0,1] op_sel_hi:[1,0]" : "=v"(d) : "v"(a)); return d;
}
__device__ inline u32 pk_sub(u32 a, u32 b) {   // a - b per half
  u32 d; asm("v_pk_add_f16 %0, %1, %2 neg_lo:[0,1] neg_hi:[0,1]" : "=v"(d) : "v"(a), "v"(b)); return d;
}
__device__ inline float dot2acc(u32 d, float acc) {  // acc += d.lo^2 + d.hi^2
  asm("v_dot2_f32_f16 %0, %1, %2, %0" : "+v"(acc) : "v"(d), "v"(d)); return acc;
}

__device__ inline void pk_cswap(u32& a, u32& b) {
  const u32 mn = pk_min(a, b), mx = pk_max(a, b);
  a = mn; b = mx;
}
__device__ inline u32 pk_sort_pair(u32 a) {   // lo' = min(halves), hi' = max
  const u32 mn = pk_min_swap(a);
  const u32 mx = pk_max_swap(a);
  return (mx & 0xFFFF0000u) | (mn & 0x0000FFFFu);
}

// ---------- cross-lane moves ----------
// DPP ctrls: 0xB1=quad xor1, 0x4E=quad xor2, 0x1B=quad xor3,
//            0x141=row_half_mirror (xor7), 0x128=row_ror:8 (xor8)
template<int CTRL>
__device__ inline u32 dpp_u(u32 x) {
  return (u32)__builtin_amdgcn_update_dpp((int)x, (int)x, CTRL, 0xF, 0xF, false);
}
template<int TM>
__device__ inline u32 dppx(u32 x) {   // value from lane t^TM
  if constexpr (TM == 1)      return dpp_u<0xB1>(x);
  else if constexpr (TM == 2) return dpp_u<0x4E>(x);
  else if constexpr (TM == 4) return dpp_u<0x141>(dpp_u<0x1B>(x));
  else                        return dpp_u<0x128>(x);
}

__device__ inline void swap32u(u32& a, u32& b) {
  asm("v_permlane32_swap_b32 %0, %1" : "+v"(a), "+v"(b));
}
__device__ inline void swap16u(u32& a, u32& b) {
  asm("v_permlane16_swap_b32 %0, %1" : "+v"(a), "+v"(b));
}
template<bool IS32>
__device__ inline void pass_perm_pk(u32 h[8]) {
  #pragma unroll
  for (int q = 0; q < 4; ++q) {
    u32 a = h[2*q], b = h[2*q + 1];
    if constexpr (IS32) swap32u(a, b); else swap16u(a, b);
    u32 mn = pk_min(a, b);
    u32 mx = pk_max(a, b);
    if constexpr (IS32) swap32u(mn, mx); else swap16u(mn, mx);
    h[2*q] = mn; h[2*q + 1] = mx;
  }
}

__device__ inline void flip_pk(u32 h[8], u32 f) {
  #pragma unroll
  for (int p = 0; p < 8; ++p) h[p] ^= f;
}

// ---------- polarized DPP block ----------
// Stored H(t) = sigma_TM(t) * x(t), sigma=+1 iff (t&TM)==0. Partner has the
// opposite sigma, so the exchanged value needs one unconditional negate:
//   H' = pk_min(H, -dpp(H))   (negate fused into the min's input modifier)
struct PolM { u32 s1, s2, s4, s8; };

template<int TM>
__device__ inline void polar_pass(u32 h[8]) {
  u32 o[8];
  #pragma unroll
  for (int p = 0; p < 8; ++p) o[p] = dppx<TM>(h[p]);
  #pragma unroll
  for (int p = 0; p < 8; ++p) h[p] = pk_min_negb(h[p], o[p]);
}

template<int TMS, bool SKIP_ENTRY>
__device__ inline void polar_block(u32 h[8], const PolM& pm) {
  if constexpr (!SKIP_ENTRY) {
    const u32 e = (TMS == 8) ? pm.s8 : (TMS == 4) ? pm.s4 : (TMS == 2) ? pm.s2 : pm.s1;
    flip_pk(h, e);
  }
  if constexpr (TMS >= 8) { polar_pass<8>(h); flip_pk(h, pm.s8 ^ pm.s4); }
  if constexpr (TMS >= 4) { polar_pass<4>(h); flip_pk(h, pm.s4 ^ pm.s2); }
  if constexpr (TMS >= 2) { polar_pass<2>(h); flip_pk(h, pm.s2 ^ pm.s1); }
  polar_pass<1>(h);
  flip_pk(h, pm.s1);   // back to plain
}

// ---------- LDS exchange (thread-xor 64/128) ----------
template<int TM>
__device__ inline void pass_lds_pk(u32 h[8], u32* buf, int t) {
  __syncthreads();   // protect prior reads of buf
  uint4* wp = (uint4*)(buf + lslot(t));
  wp[0] = make_uint4(h[0], h[1], h[2], h[3]);
  wp[1] = make_uint4(h[4], h[5], h[6], h[7]);
  __syncthreads();
  const uint4* rp = (const uint4*)(buf + lslot(t ^ TM));
  const uint4 x0 = rp[0], x1 = rp[1];
  if (t & TM) {
    h[0] = pk_max(h[0], x0.x); h[1] = pk_max(h[1], x0.y);
    h[2] = pk_max(h[2], x0.z); h[3] = pk_max(h[3], x0.w);
    h[4] = pk_max(h[4], x1.x); h[5] = pk_max(h[5], x1.y);
    h[6] = pk_max(h[6], x1.z); h[7] = pk_max(h[7], x1.w);
  } else {
    h[0] = pk_min(h[0], x0.x); h[1] = pk_min(h[1], x0.y);
    h[2] = pk_min(h[2], x0.z); h[3] = pk_min(h[3], x0.w);
    h[4] = pk_min(h[4], x1.x); h[5] = pk_min(h[5], x1.y);
    h[6] = pk_min(h[6], x1.z); h[7] = pk_min(h[7], x1.w);
  }
}

// in-register ascending tail: j = 8 (within-word), then 4, 2, 1
__device__ inline void tail_pk(u32 h[8]) {
  #pragma unroll
  for (int p = 0; p < 8; ++p) h[p] = pk_sort_pair(h[p]);
  pk_cswap(h[0], h[4]); pk_cswap(h[1], h[5]); pk_cswap(h[2], h[6]); pk_cswap(h[3], h[7]);
  pk_cswap(h[0], h[2]); pk_cswap(h[1], h[3]); pk_cswap(h[4], h[6]); pk_cswap(h[5], h[7]);
  pk_cswap(h[0], h[1]); pk_cswap(h[2], h[3]); pk_cswap(h[4], h[5]); pk_cswap(h[6], h[7]);
}

// one bitonic stage of width K (>=16), in sign-flipped space
template<int K>
__device__ inline void stage_pk(u32 h[8], u32* buf, int t, u32& cur, const PolM& pm) {
  constexpr bool FOLD = (K >= 32 && K <= 256);   // fold polar entry into flip
  const u32 f = (K >= 4096) ? 0u : ((t & (K >> 4)) ? 0x80008000u : 0u);
  u32 m = f ^ cur;
  if constexpr (FOLD)
    m ^= (K == 256) ? pm.s8 : (K == 128) ? pm.s4 : (K == 64) ? pm.s2 : pm.s1;
  flip_pk(h, m);
  cur = f;
  if constexpr (K >= 4096) pass_lds_pk<128>(h, buf, t);
  if constexpr (K >= 2048) pass_lds_pk<64>(h, buf, t);
  if constexpr (K >= 1024) pass_perm_pk<true>(h);
  if constexpr (K >= 512)  pass_perm_pk<false>(h);
  if constexpr (K >= 256)      polar_block<8, FOLD>(h, pm);
  else if constexpr (K >= 128) polar_block<4, FOLD>(h, pm);
  else if constexpr (K >= 64)  polar_block<2, FOLD>(h, pm);
  else if constexpr (K >= 32)  polar_block<1, FOLD>(h, pm);
  tail_pk(h);
}

// load 16 f32, pack immediately, run k=2,4,8 pre-stages packed.
// k=8's hi-half block (elems 8..15) sorts DESC -> flip hi signs first; the
// pending hi flip is absorbed by starting the stage chain with cur=0x80000000.
__device__ inline void load_prestage_pack(const float* __restrict__ src,
                                          u32 h[8], int t) {
  float v[16];
  const float4* s4 = (const float4*)src;
  #pragma unroll
  for (int q = 0; q < 4; ++q) {
    const float4 x = s4[t*4 + q];
    v[q*4+0] = x.x; v[q*4+1] = x.y; v[q*4+2] = x.z; v[q*4+3] = x.w;
  }
  #pragma unroll
  for (int p = 0; p < 8; ++p) {
    const f16x2 pk = __builtin_amdgcn_cvt_pkrtz(v[p], v[p + 8]);
    h[p] = __builtin_bit_cast(u32, pk);
  }
  // k=2 (j=1): (0,1)asc (2,3)desc (4,5)asc (6,7)desc — same dirs on hi halves
  pk_cswap(h[0], h[1]); pk_cswap(h[3], h[2]); pk_cswap(h[4], h[5]); pk_cswap(h[7], h[6]);
  // k=4, j=2: (0,2)(1,3)asc (4,6)(5,7)desc
  pk_cswap(h[0], h[2]); pk_cswap(h[1], h[3]); pk_cswap(h[6], h[4]); pk_cswap(h[7], h[5]);
  // k=4, j=1: (0,1)(2,3)asc (4,5)(6,7)desc
  pk_cswap(h[0], h[1]); pk_cswap(h[2], h[3]); pk_cswap(h[5], h[4]); pk_cswap(h[7], h[6]);
  // k=8: lo block asc, hi block desc -> flip hi signs, run all-asc j=4,2,1
  #pragma unroll
  for (int p = 0; p < 8; ++p) h[p] ^= 0x80000000u;
  pk_cswap(h[0], h[4]); pk_cswap(h[1], h[5]); pk_cswap(h[2], h[6]); pk_cswap(h[3], h[7]);
  pk_cswap(h[0], h[2]); pk_cswap(h[1], h[3]); pk_cswap(h[4], h[6]); pk_cswap(h[5], h[7]);
  pk_cswap(h[0], h[1]); pk_cswap(h[2], h[3]); pk_cswap(h[4], h[5]); pk_cswap(h[6], h[7]);
}

__device__ inline void sort4096_pk(u32 h[8], u32* buf, int t, const PolM& pm) {
  u32 cur = 0x80000000u;   // pending hi-half sign flip from the pre-stage
  stage_pk<16>(h, buf, t, cur, pm);
  stage_pk<32>(h, buf, t, cur, pm);
  stage_pk<64>(h, buf, t, cur, pm);
  stage_pk<128>(h, buf, t, cur, pm);
  stage_pk<256>(h, buf, t, cur, pm);
  stage_pk<512>(h, buf, t, cur, pm);
  stage_pk<1024>(h, buf, t, cur, pm);
  stage_pk<2048>(h, buf, t, cur, pm);
  stage_pk<4096>(h, buf, t, cur, pm);
  // final cur == 0 (stage 4096 has f == 0 for t < 256)
}

// kernel 1: 8192 blocks, one row each. [0,ROWS)=S rows, [ROWS,2*ROWS)=T rows.
__global__ __launch_bounds__(NTH)
void sort_one(const float* __restrict__ sE, const float* __restrict__ sS,
              const float* __restrict__ tE, const float* __restrict__ tS,
              u32* __restrict__ Ss, u32* __restrict__ Ts) {
  __shared__ u32 buf[LDSW];
  const int t = threadIdx.x;
  int r = blockIdx.x;
  const float* src;
  u32* dst;
  if (r < ROWS) {
    src = (r < HALF) ? sE + (size_t)r * N : sS + (size_t)(r - HALF) * N;
    dst = Ss + (size_t)r * ROWW;
  } else {
    r -= ROWS;
    src = (r < HALF) ? tE + (size_t)r * N : tS + (size_t)(r - HALF) * N;
    dst = Ts + (size_t)r * ROWW;
  }
  const u32 S = 0x80008000u;
  PolM pm;
  pm.s1 = (t & 1) ? S : 0u;  pm.s2 = (t & 2) ? S : 0u;
  pm.s4 = (t & 4) ? S : 0u;  pm.s8 = (t & 8) ? S : 0u;

  u32 h[8];
  load_prestage_pack(src, h, t);
  sort4096_pk(h, buf, t, pm);
  // SoA store: instruction 0 covers bytes [0,4K), instruction 1 [4K,8K) — each
  // wave writes contiguous 1KB lines. All rows share this slot map, so the
  // elementwise pairing in diff_rows stays consistent.
  uint4* d4 = (uint4*)dst;
  d4[t]       = make_uint4(h[0], h[1], h[2], h[3]);
  d4[NTH + t] = make_uint4(h[4], h[5], h[6], h[7]);
}

// kernel 2: streaming diff; per-row partials, no atomics
__global__ __launch_bounds__(NTH)
void diff_rows(const u32* __restrict__ Ss, const u32* __restrict__ Ts,
               const int* __restrict__ neg_idx, float2* __restrict__ partial) {
  __shared__ float red[2][4];
  const int t = threadIdx.x, r = blockIdx.x;

  const uint4* tp = (const uint4*)(Ts + (size_t)r * ROWW);
  const uint4 h0 = tp[t], h1 = tp[NTH + t];

  // r = ((ap)*B + b)*C + c
  const int c  = r & (CDIM - 1);
  const int b  = (r / CDIM) & (BDIM - 1);
  const int ap = r / (CDIM * BDIM);

  float posp = 0.f, negp = 0.f;
  {
    const uint4* vp = (const uint4*)(Ss + (size_t)r * ROWW);
    const uint4 w0 = vp[t], w1 = vp[NTH + t];
    posp = dot2acc(pk_sub(h0.x, w0.x), posp);
    posp = dot2acc(pk_sub(h0.y, w0.y), posp);
    posp = dot2acc(pk_sub(h0.z, w0.z), posp);
    posp = dot2acc(pk_sub(h0.w, w0.w), posp);
    posp = dot2acc(pk_sub(h1.x, w1.x), posp);
    posp = dot2acc(pk_sub(h1.y, w1.y), posp);
    posp = dot2acc(pk_sub(h1.z, w1.z), posp);
    posp = dot2acc(pk_sub(h1.w, w1.w), posp);
  }
  #pragma unroll
  for (int k = 0; k < KNEG; ++k) {
    const int nb = neg_idx[b * KNEG + k];
    const uint4* vp = (const uint4*)(Ss + ((size_t)(ap * BDIM + nb) * CDIM + c) * ROWW);
    const uint4 w0 = vp[t], w1 = vp[NTH + t];
    negp = dot2acc(pk_sub(h0.x, w0.x), negp);
    negp = dot2acc(pk_sub(h0.y, w0.y), negp);
    negp = dot2acc(pk_sub(h0.z, w0.z), negp);
    negp = dot2acc(pk_sub(h0.w, w0.w), negp);
    negp = dot2acc(pk_sub(h1.x, w1.x), negp);
    negp = dot2acc(pk_sub(h1.y, w1.y), negp);
    negp = dot2acc(pk_sub(h1.z, w1.z), negp);
    negp = dot2acc(pk_sub(h1.w, w1.w), negp);
  }

  #pragma unroll
  for (int off = 32; off > 0; off >>= 1) {
    posp += __shfl_down(posp, off, 64);
    negp += __shfl_down(negp, off, 64);
  }
  const int wid = t >> 6, lane = t & 63;
  if (lane == 0) { red[0][wid] = posp; red[1][wid] = negp; }
  __syncthreads();
  if (t == 0) {
    const float pt = red[0][0] + red[0][1] + red[0][2] + red[0][3];
    const float nt = red[1][0] + red[1][1] + red[1][2] + red[1][3];
    partial[r] = make_float2(pt, nt);
  }
}

// kernel 3: single-block reduction of 4096 partials, keyed by b
__global__ __launch_bounds__(NTH)
void finalize(const float2* __restrict__ partial, float* __restrict__ out) {
  __shared__ double rp[4], rn[4];
  const int t = threadIdx.x;
  const int wid = t >> 6, lane = t & 63;
  double res = 0.0;
  #pragma unroll
  for (int b = 0; b < BDIM; ++b) {
    double p = 0.0, n = 0.0;
    for (int idx = t; idx < 1024; idx += NTH) {     // 8 ap-chunks x 128 c
      const int a = idx >> 7, c = idx & 127;
      const float2 v = partial[a * 512 + b * 128 + c];
      p += (double)v.x; n += (double)v.y;
    }
    #pragma unroll
    for (int off = 32; off > 0; off >>= 1) {
      p += __shfl_down(p, off, 64);
      n += __shfl_down(n, off, 64);
    }
    if (lane == 0) { rp[wid] = p; rn[wid] = n; }
    __syncthreads();
    if (t == 0) {
      const double P = rp[0] + rp[1] + rp[2] + rp[3];
      const double Nn = rn[0] + rn[1] + rn[2] + rn[3];
      res += P / Nn;
    }
    __syncthreads();   // rp/rn reused next b
  }
  if (t == 0) out[0] = (float)res;
}

extern "C" void kernel_launch(void* const* d_in, const int* in_sizes, int n_in,
                              void* d_out, int out_size, void* d_ws, size_t ws_size,
                              hipStream_t stream) {
  const float* style_E = (const float*)d_in[0];
  const float* style_S = (const float*)d_in[1];
  const float* trans_E = (const float*)d_in[2];
  const float* trans_S = (const float*)d_in[3];
  const int*   neg_idx = (const int*)d_in[4];

  // ws layout: Ss packed (16.8MB), Ts packed (16.8MB), partial (32KB)
  u32*    Ss      = (u32*)d_ws;
  u32*    Ts      = Ss + (size_t)ROWS * ROWW;
  float2* partial = (float2*)(Ts + (size_t)ROWS * ROWW);

  sort_one<<<2 * ROWS, NTH, 0, stream>>>(style_E, style_S, trans_E, trans_S, Ss, Ts);
  diff_rows<<<ROWS, NTH, 0, stream>>>(Ss, Ts, neg_idx, partial);
  finalize<<<1, NTH, 0, stream>>>(partial, (float*)d_out);
}

// Round 12
// 110.649 us; speedup vs baseline: 2.1880x; 1.0752x over previous
//
#include <hip/hip_runtime.h>

// EFDM loss — reduced form:
//   pos_sum[b]  = sum over (a,p,c,j) of (sortT[a,p,b,c][j] - sortS[a,p,b,c][j])^2
//   neg_sum[b]  = sum over (a,p,k,c,j) of (sortT[a,p,b,c][j] - sortS[a,p,nb(b,k),c][j])^2
//   out = sum_b pos_sum[b]/neg_sum[b]          (the 1/(C*N) mean factors cancel)
//
// Kernel 1 (sort_one): 8192 blocks, one row per block. Packed-fp16 register
// bitonic, 16 elems/thread as 8 words (m, m+8).
//  - polarized DPP passes: h stored sign-multiplied by sigma_TM(t); exchange =
//    pk_min(h, -dpp(h)) with the negate fused into v_pk_min_f16 neg modifiers.
//  - TM=4 exchange via ds_swizzle 0x101F (1 DS op on the idle DS pipe instead
//    of 2 DPP VALU ops).
//  - LDS exchange buffer: stride-20-word slots (REVERTED to the R8/R10 map —
//    measured conflict-free; R11's stride-16+shift map caused 4.7M conflicts).
//  - packed pre-stage; coalesced SoA stores.
// Kernel 2 (diff_rows): streaming diff, per-row partials, no atomics.
// Kernel 3 (finalize): one-block double reduction.

typedef unsigned int u32;
typedef __fp16 f16x2 __attribute__((ext_vector_type(2)));

constexpr int N     = 4096;
constexpr int NTH   = 256;
constexpr int CDIM  = 128;
constexpr int BDIM  = 4;
constexpr int KNEG  = 2;
constexpr int ROWS  = 4096;
constexpr int HALF  = 2048;
constexpr int ROWW  = N / 2;   // 2048 packed words per row
constexpr int LSTRW = 20;      // words per thread-row in LDS (80B, 16B-aligned;
                               // proven conflict-free for b128 in R8/R10)
constexpr int LDSW  = NTH * LSTRW;   // 5120 words = 20480 B -> exactly 8 blocks/CU

__device__ inline int lslot(int t) { return t * LSTRW; }

// ---------- packed fp16 primitives ----------
__device__ inline u32 pk_min(u32 a, u32 b) {
  u32 d; asm("v_pk_min_f16 %0, %1, %2" : "=v"(d) : "v"(a), "v"(b)); return d;
}
__device__ inline u32 pk_max(u32 a, u32 b) {
  u32 d; asm("v_pk_max_f16 %0, %1, %2" : "=v"(d) : "v"(a), "v"(b)); return d;
}
__device__ inline u32 pk_min_negb(u32 a, u32 b) {   // min(a, -b) per half
  u32 d; asm("v_pk_min_f16 %0, %1, %2 neg_lo:[0,1] neg_hi:[0,1]" : "=v"(d) : "v"(a), "v"(b)); return d;
}
__device__ inline u32 pk_min_swap(u32 a) {  // d.lo = min(a.lo, a.hi)
  u32 d; asm("v_pk_min_f16 %0, %1, %1 op_sel:[0,1] op_sel_hi:[1,0]" : "=v"(d) : "v"(a)); return d;
}
__device__ inline u32 pk_max_swap(u32 a) {  // d.hi = max(a.lo, a.hi)
  u32 d; asm("v_pk_max_f16 %0, %1, %1 op_sel:[0,1] op_sel_hi:[1,0]" : "=v"(d) : "v"(a)); return d;
}
__device__ inline u32 pk_sub(u32 a, u32 b) {   // a - b per half
  u32 d; asm("v_pk_add_f16 %0, %1, %2 neg_lo:[0,1] neg_hi:[0,1]" : "=v"(d) : "v"(a), "v"(b)); return d;
}
__device__ inline float dot2acc(u32 d, float acc) {  // acc += d.lo^2 + d.hi^2
  asm("v_dot2_f32_f16 %0, %1, %2, %0" : "+v"(acc) : "v"(d), "v"(d)); return acc;
}

__device__ inline void pk_cswap(u32& a, u32& b) {
  const u32 mn = pk_min(a, b), mx = pk_max(a, b);
  a = mn; b = mx;
}
__device__ inline u32 pk_sort_pair(u32 a) {   // lo' = min(halves), hi' = max
  const u32 mn = pk_min_swap(a);
  const u32 mx = pk_max_swap(a);
  return (mx & 0xFFFF0000u) | (mn & 0x0000FFFFu);
}

// ---------- cross-lane moves ----------
// DPP ctrls: 0xB1=quad xor1, 0x4E=quad xor2, 0x128=row_ror:8 (xor8)
template<int CTRL>
__device__ inline u32 dpp_u(u32 x) {
  return (u32)__builtin_amdgcn_update_dpp((int)x, (int)x, CTRL, 0xF, 0xF, false);
}
template<int TM>
__device__ inline u32 dppx(u32 x) {   // value from lane t^TM
  if constexpr (TM == 1)      return dpp_u<0xB1>(x);
  else if constexpr (TM == 2) return dpp_u<0x4E>(x);
  else if constexpr (TM == 4)   // xor4 via ds_swizzle (DS pipe, 1 op)
    return (u32)__builtin_amdgcn_ds_swizzle((int)x, 0x101F);
  else                        return dpp_u<0x128>(x);
}

__device__ inline void swap32u(u32& a, u32& b) {
  asm("v_permlane32_swap_b32 %0, %1" : "+v"(a), "+v"(b));
}
__device__ inline void swap16u(u32& a, u32& b) {
  asm("v_permlane16_swap_b32 %0, %1" : "+v"(a), "+v"(b));
}
template<bool IS32>
__device__ inline void pass_perm_pk(u32 h[8]) {
  #pragma unroll
  for (int q = 0; q < 4; ++q) {
    u32 a = h[2*q], b = h[2*q + 1];
    if constexpr (IS32) swap32u(a, b); else swap16u(a, b);
    u32 mn = pk_min(a, b);
    u32 mx = pk_max(a, b);
    if constexpr (IS32) swap32u(mn, mx); else swap16u(mn, mx);
    h[2*q] = mn; h[2*q + 1] = mx;
  }
}

__device__ inline void flip_pk(u32 h[8], u32 f) {
  #pragma unroll
  for (int p = 0; p < 8; ++p) h[p] ^= f;
}

// ---------- polarized exchange block ----------
// Stored H(t) = sigma_TM(t) * x(t), sigma=+1 iff (t&TM)==0. Partner has the
// opposite sigma, so the exchange needs one unconditional fused negate:
//   H' = pk_min(H, -xchg(H))
struct PolM { u32 s1, s2, s4, s8; };

template<int TM>
__device__ inline void polar_pass(u32 h[8]) {
  u32 o[8];
  #pragma unroll
  for (int p = 0; p < 8; ++p) o[p] = dppx<TM>(h[p]);
  #pragma unroll
  for (int p = 0; p < 8; ++p) h[p] = pk_min_negb(h[p], o[p]);
}

template<int TMS, bool SKIP_ENTRY>
__device__ inline void polar_block(u32 h[8], const PolM& pm) {
  if constexpr (!SKIP_ENTRY) {
    const u32 e = (TMS == 8) ? pm.s8 : (TMS == 4) ? pm.s4 : (TMS == 2) ? pm.s2 : pm.s1;
    flip_pk(h, e);
  }
  if constexpr (TMS >= 8) { polar_pass<8>(h); flip_pk(h, pm.s8 ^ pm.s4); }
  if constexpr (TMS >= 4) { polar_pass<4>(h); flip_pk(h, pm.s4 ^ pm.s2); }
  if constexpr (TMS >= 2) { polar_pass<2>(h); flip_pk(h, pm.s2 ^ pm.s1); }
  polar_pass<1>(h);
  flip_pk(h, pm.s1);   // back to plain
}

// ---------- LDS exchange (thread-xor 64/128) ----------
template<int TM>
__device__ inline void pass_lds_pk(u32 h[8], u32* buf, int t) {
  __syncthreads();   // protect prior reads of buf
  uint4* wp = (uint4*)(buf + lslot(t));
  wp[0] = make_uint4(h[0], h[1], h[2], h[3]);
  wp[1] = make_uint4(h[4], h[5], h[6], h[7]);
  __syncthreads();
  const uint4* rp = (const uint4*)(buf + lslot(t ^ TM));
  const uint4 x0 = rp[0], x1 = rp[1];
  if (t & TM) {
    h[0] = pk_max(h[0], x0.x); h[1] = pk_max(h[1], x0.y);
    h[2] = pk_max(h[2], x0.z); h[3] = pk_max(h[3], x0.w);
    h[4] = pk_max(h[4], x1.x); h[5] = pk_max(h[5], x1.y);
    h[6] = pk_max(h[6], x1.z); h[7] = pk_max(h[7], x1.w);
  } else {
    h[0] = pk_min(h[0], x0.x); h[1] = pk_min(h[1], x0.y);
    h[2] = pk_min(h[2], x0.z); h[3] = pk_min(h[3], x0.w);
    h[4] = pk_min(h[4], x1.x); h[5] = pk_min(h[5], x1.y);
    h[6] = pk_min(h[6], x1.z); h[7] = pk_min(h[7], x1.w);
  }
}

// in-register ascending tail: j = 8 (within-word), then 4, 2, 1
__device__ inline void tail_pk(u32 h[8]) {
  #pragma unroll
  for (int p = 0; p < 8; ++p) h[p] = pk_sort_pair(h[p]);
  pk_cswap(h[0], h[4]); pk_cswap(h[1], h[5]); pk_cswap(h[2], h[6]); pk_cswap(h[3], h[7]);
  pk_cswap(h[0], h[2]); pk_cswap(h[1], h[3]); pk_cswap(h[4], h[6]); pk_cswap(h[5], h[7]);
  pk_cswap(h[0], h[1]); pk_cswap(h[2], h[3]); pk_cswap(h[4], h[5]); pk_cswap(h[6], h[7]);
}

// one bitonic stage of width K (>=16), in sign-flipped space
template<int K>
__device__ inline void stage_pk(u32 h[8], u32* buf, int t, u32& cur, const PolM& pm) {
  constexpr bool FOLD = (K >= 32 && K <= 256);   // fold polar entry into flip
  const u32 f = (K >= 4096) ? 0u : ((t & (K >> 4)) ? 0x80008000u : 0u);
  u32 m = f ^ cur;
  if constexpr (FOLD)
    m ^= (K == 256) ? pm.s8 : (K == 128) ? pm.s4 : (K == 64) ? pm.s2 : pm.s1;
  flip_pk(h, m);
  cur = f;
  if constexpr (K >= 4096) pass_lds_pk<128>(h, buf, t);
  if constexpr (K >= 2048) pass_lds_pk<64>(h, buf, t);
  if constexpr (K >= 1024) pass_perm_pk<true>(h);
  if constexpr (K >= 512)  pass_perm_pk<false>(h);
  if constexpr (K >= 256)      polar_block<8, FOLD>(h, pm);
  else if constexpr (K >= 128) polar_block<4, FOLD>(h, pm);
  else if constexpr (K >= 64)  polar_block<2, FOLD>(h, pm);
  else if constexpr (K >= 32)  polar_block<1, FOLD>(h, pm);
  tail_pk(h);
}

// load 16 f32, pack immediately, run k=2,4,8 pre-stages packed.
// k=8's hi-half block (elems 8..15) sorts DESC -> flip hi signs first; the
// pending hi flip is absorbed by starting the stage chain with cur=0x80000000.
__device__ inline void load_prestage_pack(const float* __restrict__ src,
                                          u32 h[8], int t) {
  float v[16];
  const float4* s4 = (const float4*)src;
  #pragma unroll
  for (int q = 0; q < 4; ++q) {
    const float4 x = s4[t*4 + q];
    v[q*4+0] = x.x; v[q*4+1] = x.y; v[q*4+2] = x.z; v[q*4+3] = x.w;
  }
  #pragma unroll
  for (int p = 0; p < 8; ++p) {
    const f16x2 pk = __builtin_amdgcn_cvt_pkrtz(v[p], v[p + 8]);
    h[p] = __builtin_bit_cast(u32, pk);
  }
  // k=2 (j=1): (0,1)asc (2,3)desc (4,5)asc (6,7)desc — same dirs on hi halves
  pk_cswap(h[0], h[1]); pk_cswap(h[3], h[2]); pk_cswap(h[4], h[5]); pk_cswap(h[7], h[6]);
  // k=4, j=2: (0,2)(1,3)asc (4,6)(5,7)desc
  pk_cswap(h[0], h[2]); pk_cswap(h[1], h[3]); pk_cswap(h[6], h[4]); pk_cswap(h[7], h[5]);
  // k=4, j=1: (0,1)(2,3)asc (4,5)(6,7)desc
  pk_cswap(h[0], h[1]); pk_cswap(h[2], h[3]); pk_cswap(h[5], h[4]); pk_cswap(h[7], h[6]);
  // k=8: lo block asc, hi block desc -> flip hi signs, run all-asc j=4,2,1
  #pragma unroll
  for (int p = 0; p < 8; ++p) h[p] ^= 0x80000000u;
  pk_cswap(h[0], h[4]); pk_cswap(h[1], h[5]); pk_cswap(h[2], h[6]); pk_cswap(h[3], h[7]);
  pk_cswap(h[0], h[2]); pk_cswap(h[1], h[3]); pk_cswap(h[4], h[6]); pk_cswap(h[5], h[7]);
  pk_cswap(h[0], h[1]); pk_cswap(h[2], h[3]); pk_cswap(h[4], h[5]); pk_cswap(h[6], h[7]);
}

__device__ inline void sort4096_pk(u32 h[8], u32* buf, int t, const PolM& pm) {
  u32 cur = 0x80000000u;   // pending hi-half sign flip from the pre-stage
  stage_pk<16>(h, buf, t, cur, pm);
  stage_pk<32>(h, buf, t, cur, pm);
  stage_pk<64>(h, buf, t, cur, pm);
  stage_pk<128>(h, buf, t, cur, pm);
  stage_pk<256>(h, buf, t, cur, pm);
  stage_pk<512>(h, buf, t, cur, pm);
  stage_pk<1024>(h, buf, t, cur, pm);
  stage_pk<2048>(h, buf, t, cur, pm);
  stage_pk<4096>(h, buf, t, cur, pm);
  // final cur == 0 (stage 4096 has f == 0 for t < 256)
}

// kernel 1: 8192 blocks, one row each. [0,ROWS)=S rows, [ROWS,2*ROWS)=T rows.
__global__ __launch_bounds__(NTH)
void sort_one(const float* __restrict__ sE, const float* __restrict__ sS,
              const float* __restrict__ tE, const float* __restrict__ tS,
              u32* __restrict__ Ss, u32* __restrict__ Ts) {
  __shared__ u32 buf[LDSW];
  const int t = threadIdx.x;
  int r = blockIdx.x;
  const float* src;
  u32* dst;
  if (r < ROWS) {
    src = (r < HALF) ? sE + (size_t)r * N : sS + (size_t)(r - HALF) * N;
    dst = Ss + (size_t)r * ROWW;
  } else {
    r -= ROWS;
    src = (r < HALF) ? tE + (size_t)r * N : tS + (size_t)(r - HALF) * N;
    dst = Ts + (size_t)r * ROWW;
  }
  const u32 S = 0x80008000u;
  PolM pm;
  pm.s1 = (t & 1) ? S : 0u;  pm.s2 = (t & 2) ? S : 0u;
  pm.s4 = (t & 4) ? S : 0u;  pm.s8 = (t & 8) ? S : 0u;

  u32 h[8];
  load_prestage_pack(src, h, t);
  sort4096_pk(h, buf, t, pm);
  // SoA store: instruction 0 covers bytes [0,4K), instruction 1 [4K,8K) — each
  // wave writes contiguous 1KB lines. All rows share this slot map, so the
  // elementwise pairing in diff_rows stays consistent.
  uint4* d4 = (uint4*)dst;
  d4[t]       = make_uint4(h[0], h[1], h[2], h[3]);
  d4[NTH + t] = make_uint4(h[4], h[5], h[6], h[7]);
}

// kernel 2: streaming diff; per-row partials, no atomics
__global__ __launch_bounds__(NTH)
void diff_rows(const u32* __restrict__ Ss, const u32* __restrict__ Ts,
               const int* __restrict__ neg_idx, float2* __restrict__ partial) {
  __shared__ float red[2][4];
  const int t = threadIdx.x, r = blockIdx.x;

  const uint4* tp = (const uint4*)(Ts + (size_t)r * ROWW);
  const uint4 h0 = tp[t], h1 = tp[NTH + t];

  // r = ((ap)*B + b)*C + c
  const int c  = r & (CDIM - 1);
  const int b  = (r / CDIM) & (BDIM - 1);
  const int ap = r / (CDIM * BDIM);

  float posp = 0.f, negp = 0.f;
  {
    const uint4* vp = (const uint4*)(Ss + (size_t)r * ROWW);
    const uint4 w0 = vp[t], w1 = vp[NTH + t];
    posp = dot2acc(pk_sub(h0.x, w0.x), posp);
    posp = dot2acc(pk_sub(h0.y, w0.y), posp);
    posp = dot2acc(pk_sub(h0.z, w0.z), posp);
    posp = dot2acc(pk_sub(h0.w, w0.w), posp);
    posp = dot2acc(pk_sub(h1.x, w1.x), posp);
    posp = dot2acc(pk_sub(h1.y, w1.y), posp);
    posp = dot2acc(pk_sub(h1.z, w1.z), posp);
    posp = dot2acc(pk_sub(h1.w, w1.w), posp);
  }
  #pragma unroll
  for (int k = 0; k < KNEG; ++k) {
    const int nb = neg_idx[b * KNEG + k];
    const uint4* vp = (const uint4*)(Ss + ((size_t)(ap * BDIM + nb) * CDIM + c) * ROWW);
    const uint4 w0 = vp[t], w1 = vp[NTH + t];
    negp = dot2acc(pk_sub(h0.x, w0.x), negp);
    negp = dot2acc(pk_sub(h0.y, w0.y), negp);
    negp = dot2acc(pk_sub(h0.z, w0.z), negp);
    negp = dot2acc(pk_sub(h0.w, w0.w), negp);
    negp = dot2acc(pk_sub(h1.x, w1.x), negp);
    negp = dot2acc(pk_sub(h1.y, w1.y), negp);
    negp = dot2acc(pk_sub(h1.z, w1.z), negp);
    negp = dot2acc(pk_sub(h1.w, w1.w), negp);
  }

  #pragma unroll
  for (int off = 32; off > 0; off >>= 1) {
    posp += __shfl_down(posp, off, 64);
    negp += __shfl_down(negp, off, 64);
  }
  const int wid = t >> 6, lane = t & 63;
  if (lane == 0) { red[0][wid] = posp; red[1][wid] = negp; }
  __syncthreads();
  if (t == 0) {
    const float pt = red[0][0] + red[0][1] + red[0][2] + red[0][3];
    const float nt = red[1][0] + red[1][1] + red[1][2] + red[1][3];
    partial[r] = make_float2(pt, nt);
  }
}

// kernel 3: single-block reduction of 4096 partials, keyed by b
__global__ __launch_bounds__(NTH)
void finalize(const float2* __restrict__ partial, float* __restrict__ out) {
  __shared__ double rp[4], rn[4];
  const int t = threadIdx.x;
  const int wid = t >> 6, lane = t & 63;
  double res = 0.0;
  #pragma unroll
  for (int b = 0; b < BDIM; ++b) {
    double p = 0.0, n = 0.0;
    for (int idx = t; idx < 1024; idx += NTH) {     // 8 ap-chunks x 128 c
      const int a = idx >> 7, c = idx & 127;
      const float2 v = partial[a * 512 + b * 128 + c];
      p += (double)v.x; n += (double)v.y;
    }
    #pragma unroll
    for (int off = 32; off > 0; off >>= 1) {
      p += __shfl_down(p, off, 64);
      n += __shfl_down(n, off, 64);
    }
    if (lane == 0) { rp[wid] = p; rn[wid] = n; }
    __syncthreads();
    if (t == 0) {
      const double P = rp[0] + rp[1] + rp[2] + rp[3];
      const double Nn = rn[0] + rn[1] + rn[2] + rn[3];
      res += P / Nn;
    }
    __syncthreads();   // rp/rn reused next b
  }
  if (t == 0) out[0] = (float)res;
}

extern "C" void kernel_launch(void* const* d_in, const int* in_sizes, int n_in,
                              void* d_out, int out_size, void* d_ws, size_t ws_size,
                              hipStream_t stream) {
  const float* style_E = (const float*)d_in[0];
  const float* style_S = (const float*)d_in[1];
  const float* trans_E = (const float*)d_in[2];
  const float* trans_S = (const float*)d_in[3];
  const int*   neg_idx = (const int*)d_in[4];

  // ws layout: Ss packed (16.8MB), Ts packed (16.8MB), partial (32KB)
  u32*    Ss      = (u32*)d_ws;
  u32*    Ts      = Ss + (size_t)ROWS * ROWW;
  float2* partial = (float2*)(Ts + (size_t)ROWS * ROWW);

  sort_one<<<2 * ROWS, NTH, 0, stream>>>(style_E, style_S, trans_E, trans_S, Ss, Ts);
  diff_rows<<<ROWS, NTH, 0, stream>>>(Ss, Ts, neg_idx, partial);
  finalize<<<1, NTH, 0, stream>>>(partial, (float*)d_out);
}

// Round 13
// 103.949 us; speedup vs baseline: 2.3290x; 1.0645x over previous
//
#include <hip/hip_runtime.h>

// EFDM loss — reduced form:
//   pos_sum[b]  = sum over (a,p,c,j) of (sortT[a,p,b,c][j] - sortS[a,p,b,c][j])^2
//   neg_sum[b]  = sum over (a,p,k,c,j) of (sortT[a,p,b,c][j] - sortS[a,p,nb(b,k),c][j])^2
//   out = sum_b pos_sum[b]/neg_sum[b]          (the 1/(C*N) mean factors cancel)
//
// Kernel 1 (sort_pair): 4096 blocks, block r sorts BOTH S-row r and T-row r in
// one instruction stream: word p = [S elem (lo fp16), T elem (hi fp16)].
// Every network op is per-half independent (pk_min/max, whole-word lane moves,
// sign-XOR masks), so two rows ride one sort. Tail passes are now pure 2-op
// word-pair cswaps (the 3-op in-word sort_pair pass is gone). Unpack at store
// via v_perm_b32; all rows share the same rank->slot map so diff is unchanged.
//  - polarized DPP/swizzle passes (pk_min with fused neg on exchanged value)
//  - TM=4 via ds_swizzle 0x101F; TM=16/32 via permlane swap butterfly
//  - LDS (TM=64/128): stride-20-word slots, proven conflict-free
// Kernel 2 (diff_rows): streaming diff, per-row partials, no atomics.
// Kernel 3 (finalize): one-block double reduction.

typedef unsigned int u32;
typedef __fp16 f16x2 __attribute__((ext_vector_type(2)));

constexpr int N     = 4096;
constexpr int NTH   = 256;
constexpr int CDIM  = 128;
constexpr int BDIM  = 4;
constexpr int KNEG  = 2;
constexpr int ROWS  = 4096;
constexpr int HALF  = 2048;
constexpr int ROWW  = N / 2;   // 2048 packed words per row
constexpr int LSTRW = 20;      // words per thread slot in LDS (80B; 16 used)
constexpr int LDSW  = NTH * LSTRW;   // 20480 B -> 8 blocks/CU

__device__ inline int lslot(int t) { return t * LSTRW; }

// ---------- packed fp16 primitives ----------
__device__ inline u32 pk_min(u32 a, u32 b) {
  u32 d; asm("v_pk_min_f16 %0, %1, %2" : "=v"(d) : "v"(a), "v"(b)); return d;
}
__device__ inline u32 pk_max(u32 a, u32 b) {
  u32 d; asm("v_pk_max_f16 %0, %1, %2" : "=v"(d) : "v"(a), "v"(b)); return d;
}
__device__ inline u32 pk_min_negb(u32 a, u32 b) {   // min(a, -b) per half
  u32 d; asm("v_pk_min_f16 %0, %1, %2 neg_lo:[0,1] neg_hi:[0,1]" : "=v"(d) : "v"(a), "v"(b)); return d;
}
__device__ inline u32 pk_sub(u32 a, u32 b) {   // a - b per half
  u32 d; asm("v_pk_add_f16 %0, %1, %2 neg_lo:[0,1] neg_hi:[0,1]" : "=v"(d) : "v"(a), "v"(b)); return d;
}
__device__ inline float dot2acc(u32 d, float acc) {  // acc += d.lo^2 + d.hi^2
  asm("v_dot2_f32_f16 %0, %1, %2, %0" : "+v"(acc) : "v"(d), "v"(d)); return acc;
}
__device__ inline void pk_cswap(u32& a, u32& b) {
  const u32 mn = pk_min(a, b), mx = pk_max(a, b);
  a = mn; b = mx;
}

// ---------- cross-lane moves ----------
// DPP ctrls: 0xB1=quad xor1, 0x4E=quad xor2, 0x128=row_ror:8 (xor8)
template<int CTRL>
__device__ inline u32 dpp_u(u32 x) {
  return (u32)__builtin_amdgcn_update_dpp((int)x, (int)x, CTRL, 0xF, 0xF, false);
}
template<int TM>
__device__ inline u32 dppx(u32 x) {   // value from lane t^TM
  if constexpr (TM == 1)      return dpp_u<0xB1>(x);
  else if constexpr (TM == 2) return dpp_u<0x4E>(x);
  else if constexpr (TM == 4)   // xor4 via ds_swizzle (DS pipe)
    return (u32)__builtin_amdgcn_ds_swizzle((int)x, 0x101F);
  else                        return dpp_u<0x128>(x);
}
__device__ inline void swap32u(u32& a, u32& b) {
  asm("v_permlane32_swap_b32 %0, %1" : "+v"(a), "+v"(b));
}
__device__ inline void swap16u(u32& a, u32& b) {
  asm("v_permlane16_swap_b32 %0, %1" : "+v"(a), "+v"(b));
}

__device__ inline void flip16(u32 h[16], u32 f) {
  #pragma unroll
  for (int p = 0; p < 16; ++p) h[p] ^= f;
}

// ---------- polarized exchange block (on 16 words) ----------
// Stored H(t) = sigma_TM(t) * x(t), sigma=+1 iff (t&TM)==0. Partner has the
// opposite sigma: H' = pk_min(H, -xchg(H)) with the negate fused.
struct PolM { u32 s1, s2, s4, s8; };

template<int TM>
__device__ inline void polar_pass16(u32 h[16]) {
  #pragma unroll
  for (int g = 0; g < 16; g += 8) {
    u32 o[8];
    #pragma unroll
    for (int p = 0; p < 8; ++p) o[p] = dppx<TM>(h[g + p]);
    #pragma unroll
    for (int p = 0; p < 8; ++p) h[g + p] = pk_min_negb(h[g + p], o[p]);
  }
}

template<int TMS, bool SKIP_ENTRY>
__device__ inline void polar_block16(u32 h[16], const PolM& pm) {
  if constexpr (!SKIP_ENTRY) {
    const u32 e = (TMS == 8) ? pm.s8 : (TMS == 4) ? pm.s4 : (TMS == 2) ? pm.s2 : pm.s1;
    flip16(h, e);
  }
  if constexpr (TMS >= 8) { polar_pass16<8>(h); flip16(h, pm.s8 ^ pm.s4); }
  if constexpr (TMS >= 4) { polar_pass16<4>(h); flip16(h, pm.s4 ^ pm.s2); }
  if constexpr (TMS >= 2) { polar_pass16<2>(h); flip16(h, pm.s2 ^ pm.s1); }
  polar_pass16<1>(h);
  flip16(h, pm.s1);   // back to plain
}

// lane-xor 16/32 butterfly on word PAIRs: positional min/max, no polarity
template<bool IS32>
__device__ inline void pass_perm16(u32 h[16]) {
  #pragma unroll
  for (int q = 0; q < 8; ++q) {
    u32 a = h[2*q], b = h[2*q + 1];
    if constexpr (IS32) swap32u(a, b); else swap16u(a, b);
    u32 mn = pk_min(a, b);
    u32 mx = pk_max(a, b);
    if constexpr (IS32) swap32u(mn, mx); else swap16u(mn, mx);
    h[2*q] = mn; h[2*q + 1] = mx;
  }
}

// thread-xor 64/128 via LDS; keep decision wave-uniform
template<int TM>
__device__ inline void pass_lds16(u32 h[16], u32* buf, int t) {
  __syncthreads();   // protect prior reads of buf
  uint4* wp = (uint4*)(buf + lslot(t));
  wp[0] = make_uint4(h[0],  h[1],  h[2],  h[3]);
  wp[1] = make_uint4(h[4],  h[5],  h[6],  h[7]);
  wp[2] = make_uint4(h[8],  h[9],  h[10], h[11]);
  wp[3] = make_uint4(h[12], h[13], h[14], h[15]);
  __syncthreads();
  const uint4* rp = (const uint4*)(buf + lslot(t ^ TM));
  const uint4 x0 = rp[0], x1 = rp[1], x2 = rp[2], x3 = rp[3];
  if (t & TM) {
    h[0]  = pk_max(h[0],  x0.x); h[1]  = pk_max(h[1],  x0.y);
    h[2]  = pk_max(h[2],  x0.z); h[3]  = pk_max(h[3],  x0.w);
    h[4]  = pk_max(h[4],  x1.x); h[5]  = pk_max(h[5],  x1.y);
    h[6]  = pk_max(h[6],  x1.z); h[7]  = pk_max(h[7],  x1.w);
    h[8]  = pk_max(h[8],  x2.x); h[9]  = pk_max(h[9],  x2.y);
    h[10] = pk_max(h[10], x2.z); h[11] = pk_max(h[11], x2.w);
    h[12] = pk_max(h[12], x3.x); h[13] = pk_max(h[13], x3.y);
    h[14] = pk_max(h[14], x3.z); h[15] = pk_max(h[15], x3.w);
  } else {
    h[0]  = pk_min(h[0],  x0.x); h[1]  = pk_min(h[1],  x0.y);
    h[2]  = pk_min(h[2],  x0.z); h[3]  = pk_min(h[3],  x0.w);
    h[4]  = pk_min(h[4],  x1.x); h[5]  = pk_min(h[5],  x1.y);
    h[6]  = pk_min(h[6],  x1.z); h[7]  = pk_min(h[7],  x1.w);
    h[8]  = pk_min(h[8],  x2.x); h[9]  = pk_min(h[9],  x2.y);
    h[10] = pk_min(h[10], x2.z); h[11] = pk_min(h[11], x2.w);
    h[12] = pk_min(h[12], x3.x); h[13] = pk_min(h[13], x3.y);
    h[14] = pk_min(h[14], x3.z); h[15] = pk_min(h[15], x3.w);
  }
}

// pre-stage passes (k<=8): direction static from word index p
template<int K, int J>
__device__ inline void local_pass16(u32 h[16]) {
  #pragma unroll
  for (int p = 0; p < 16; ++p)
    if ((p & J) == 0) {
      if ((p & K) == 0) pk_cswap(h[p], h[p ^ J]);
      else              pk_cswap(h[p ^ J], h[p]);
    }
}

// in-register ascending tail: j = 8, 4, 2, 1 — all plain word-pair cswaps
__device__ inline void tail16(u32 h[16]) {
  #pragma unroll
  for (int p = 0; p < 16; ++p) if ((p & 8) == 0) pk_cswap(h[p], h[p ^ 8]);
  #pragma unroll
  for (int p = 0; p < 16; ++p) if ((p & 4) == 0) pk_cswap(h[p], h[p ^ 4]);
  #pragma unroll
  for (int p = 0; p < 16; ++p) if ((p & 2) == 0) pk_cswap(h[p], h[p ^ 2]);
  #pragma unroll
  for (int p = 0; p < 16; ++p) if ((p & 1) == 0) pk_cswap(h[p], h[p ^ 1]);
}

// one bitonic stage of width K (>=16), in sign-flipped space
template<int K>
__device__ inline void stage16(u32 h[16], u32* buf, int t, u32& cur, const PolM& pm) {
  constexpr bool FOLD = (K >= 32 && K <= 256);   // fold polar entry into flip
  const u32 f = (K >= 4096) ? 0u : ((t & (K >> 4)) ? 0x80008000u : 0u);
  u32 m = f ^ cur;
  if constexpr (FOLD)
    m ^= (K == 256) ? pm.s8 : (K == 128) ? pm.s4 : (K == 64) ? pm.s2 : pm.s1;
  flip16(h, m);
  cur = f;
  if constexpr (K >= 4096) pass_lds16<128>(h, buf, t);
  if constexpr (K >= 2048) pass_lds16<64>(h, buf, t);
  if constexpr (K >= 1024) pass_perm16<true>(h);
  if constexpr (K >= 512)  pass_perm16<false>(h);
  if constexpr (K >= 256)      polar_block16<8, FOLD>(h, pm);
  else if constexpr (K >= 128) polar_block16<4, FOLD>(h, pm);
  else if constexpr (K >= 64)  polar_block16<2, FOLD>(h, pm);
  else if constexpr (K >= 32)  polar_block16<1, FOLD>(h, pm);
  tail16(h);
}

// kernel 1: 4096 blocks; block r sorts S-row r (lo halves) + T-row r (hi halves)
__global__ __launch_bounds__(NTH)
void sort_pair(const float* __restrict__ sE, const float* __restrict__ sS,
               const float* __restrict__ tE, const float* __restrict__ tS,
               u32* __restrict__ Ss, u32* __restrict__ Ts) {
  __shared__ u32 buf[LDSW];
  const int t = threadIdx.x, r = blockIdx.x;
  const float* srcS = (r < HALF) ? sE + (size_t)r * N : sS + (size_t)(r - HALF) * N;
  const float* srcT = (r < HALF) ? tE + (size_t)r * N : tS + (size_t)(r - HALF) * N;

  // load + pack: word p = [S elem t*16+p (lo), T elem t*16+p (hi)]
  u32 h[16];
  {
    const float4* a4 = (const float4*)srcS;
    const float4* b4 = (const float4*)srcT;
    #pragma unroll
    for (int q = 0; q < 4; ++q) {
      const float4 xa = a4[t*4 + q];
      const float4 xb = b4[t*4 + q];
      const f16x2 p0 = __builtin_amdgcn_cvt_pkrtz(xa.x, xb.x);
      const f16x2 p1 = __builtin_amdgcn_cvt_pkrtz(xa.y, xb.y);
      const f16x2 p2 = __builtin_amdgcn_cvt_pkrtz(xa.z, xb.z);
      const f16x2 p3 = __builtin_amdgcn_cvt_pkrtz(xa.w, xb.w);
      h[q*4+0] = __builtin_bit_cast(u32, p0);
      h[q*4+1] = __builtin_bit_cast(u32, p1);
      h[q*4+2] = __builtin_bit_cast(u32, p2);
      h[q*4+3] = __builtin_bit_cast(u32, p3);
    }
  }

  // pre-stages k=2,4,8 (directions static by word index; desc = swapped args)
  local_pass16<2, 1>(h);
  local_pass16<4, 2>(h); local_pass16<4, 1>(h);
  local_pass16<8, 4>(h); local_pass16<8, 2>(h); local_pass16<8, 1>(h);

  const u32 S = 0x80008000u;
  PolM pm;
  pm.s1 = (t & 1) ? S : 0u;  pm.s2 = (t & 2) ? S : 0u;
  pm.s4 = (t & 4) ? S : 0u;  pm.s8 = (t & 8) ? S : 0u;

  u32 cur = 0;
  stage16<16>(h, buf, t, cur, pm);
  stage16<32>(h, buf, t, cur, pm);
  stage16<64>(h, buf, t, cur, pm);
  stage16<128>(h, buf, t, cur, pm);
  stage16<256>(h, buf, t, cur, pm);
  stage16<512>(h, buf, t, cur, pm);
  stage16<1024>(h, buf, t, cur, pm);
  stage16<2048>(h, buf, t, cur, pm);
  stage16<4096>(h, buf, t, cur, pm);
  // cur == 0 at the end (stage 4096 has f == 0 for all t)

  // unpack: A-word q = [lo(h[2q]), lo(h[2q+1])], B-word q = [hi(h[2q]), hi(h[2q+1])]
  u32 A[8], B[8];
  #pragma unroll
  for (int q = 0; q < 8; ++q) {
    A[q] = __builtin_amdgcn_perm(h[2*q+1], h[2*q], 0x05040100u);
    B[q] = __builtin_amdgcn_perm(h[2*q+1], h[2*q], 0x07060302u);
  }
  uint4* dA = (uint4*)(Ss + (size_t)r * ROWW);
  uint4* dB = (uint4*)(Ts + (size_t)r * ROWW);
  dA[t]       = make_uint4(A[0], A[1], A[2], A[3]);
  dA[NTH + t] = make_uint4(A[4], A[5], A[6], A[7]);
  dB[t]       = make_uint4(B[0], B[1], B[2], B[3]);
  dB[NTH + t] = make_uint4(B[4], B[5], B[6], B[7]);
}

// kernel 2: streaming diff; per-row partials, no atomics
__global__ __launch_bounds__(NTH)
void diff_rows(const u32* __restrict__ Ss, const u32* __restrict__ Ts,
               const int* __restrict__ neg_idx, float2* __restrict__ partial) {
  __shared__ float red[2][4];
  const int t = threadIdx.x, r = blockIdx.x;

  const uint4* tp = (const uint4*)(Ts + (size_t)r * ROWW);
  const uint4 h0 = tp[t], h1 = tp[NTH + t];

  // r = ((ap)*B + b)*C + c
  const int c  = r & (CDIM - 1);
  const int b  = (r / CDIM) & (BDIM - 1);
  const int ap = r / (CDIM * BDIM);

  float posp = 0.f, negp = 0.f;
  {
    const uint4* vp = (const uint4*)(Ss + (size_t)r * ROWW);
    const uint4 w0 = vp[t], w1 = vp[NTH + t];
    posp = dot2acc(pk_sub(h0.x, w0.x), posp);
    posp = dot2acc(pk_sub(h0.y, w0.y), posp);
    posp = dot2acc(pk_sub(h0.z, w0.z), posp);
    posp = dot2acc(pk_sub(h0.w, w0.w), posp);
    posp = dot2acc(pk_sub(h1.x, w1.x), posp);
    posp = dot2acc(pk_sub(h1.y, w1.y), posp);
    posp = dot2acc(pk_sub(h1.z, w1.z), posp);
    posp = dot2acc(pk_sub(h1.w, w1.w), posp);
  }
  #pragma unroll
  for (int k = 0; k < KNEG; ++k) {
    const int nb = neg_idx[b * KNEG + k];
    const uint4* vp = (const uint4*)(Ss + ((size_t)(ap * BDIM + nb) * CDIM + c) * ROWW);
    const uint4 w0 = vp[t], w1 = vp[NTH + t];
    negp = dot2acc(pk_sub(h0.x, w0.x), negp);
    negp = dot2acc(pk_sub(h0.y, w0.y), negp);
    negp = dot2acc(pk_sub(h0.z, w0.z), negp);
    negp = dot2acc(pk_sub(h0.w, w0.w), negp);
    negp = dot2acc(pk_sub(h1.x, w1.x), negp);
    negp = dot2acc(pk_sub(h1.y, w1.y), negp);
    negp = dot2acc(pk_sub(h1.z, w1.z), negp);
    negp = dot2acc(pk_sub(h1.w, w1.w), negp);
  }

  #pragma unroll
  for (int off = 32; off > 0; off >>= 1) {
    posp += __shfl_down(posp, off, 64);
    negp += __shfl_down(negp, off, 64);
  }
  const int wid = t >> 6, lane = t & 63;
  if (lane == 0) { red[0][wid] = posp; red[1][wid] = negp; }
  __syncthreads();
  if (t == 0) {
    const float pt = red[0][0] + red[0][1] + red[0][2] + red[0][3];
    const float nt = red[1][0] + red[1][1] + red[1][2] + red[1][3];
    partial[r] = make_float2(pt, nt);
  }
}

// kernel 3: single-block reduction of 4096 partials, keyed by b
__global__ __launch_bounds__(NTH)
void finalize(const float2* __restrict__ partial, float* __restrict__ out) {
  __shared__ double rp[4], rn[4];
  const int t = threadIdx.x;
  const int wid = t >> 6, lane = t & 63;
  double res = 0.0;
  #pragma unroll
  for (int b = 0; b < BDIM; ++b) {
    double p = 0.0, n = 0.0;
    for (int idx = t; idx < 1024; idx += NTH) {     // 8 ap-chunks x 128 c
      const int a = idx >> 7, c = idx & 127;
      const float2 v = partial[a * 512 + b * 128 + c];
      p += (double)v.x; n += (double)v.y;
    }
    #pragma unroll
    for (int off = 32; off > 0; off >>= 1) {
      p += __shfl_down(p, off, 64);
      n += __shfl_down(n, off, 64);
    }
    if (lane == 0) { rp[wid] = p; rn[wid] = n; }
    __syncthreads();
    if (t == 0) {
      const double P = rp[0] + rp[1] + rp[2] + rp[3];
      const double Nn = rn[0] + rn[1] + rn[2] + rn[3];
      res += P / Nn;
    }
    __syncthreads();   // rp/rn reused next b
  }
  if (t == 0) out[0] = (float)res;
}

extern "C" void kernel_launch(void* const* d_in, const int* in_sizes, int n_in,
                              void* d_out, int out_size, void* d_ws, size_t ws_size,
                              hipStream_t stream) {
  const float* style_E = (const float*)d_in[0];
  const float* style_S = (const float*)d_in[1];
  const float* trans_E = (const float*)d_in[2];
  const float* trans_S = (const float*)d_in[3];
  const int*   neg_idx = (const int*)d_in[4];

  // ws layout: Ss packed (16.8MB), Ts packed (16.8MB), partial (32KB)
  u32*    Ss      = (u32*)d_ws;
  u32*    Ts      = Ss + (size_t)ROWS * ROWW;
  float2* partial = (float2*)(Ts + (size_t)ROWS * ROWW);

  sort_pair<<<ROWS, NTH, 0, stream>>>(style_E, style_S, trans_E, trans_S, Ss, Ts);
  diff_rows<<<ROWS, NTH, 0, stream>>>(Ss, Ts, neg_idx, partial);
  finalize<<<1, NTH, 0, stream>>>(partial, (float*)d_out);
}